// Round 2
// baseline (3224.048 us; speedup 1.0000x reference)
//
#include <hip/hip_runtime.h>

typedef __attribute__((ext_vector_type(8))) short bf16x8;
typedef __attribute__((ext_vector_type(4))) float f32x4;

#define N_NODES 50000
#define N_EDGES 800000
#define DIM 128
#define N_GRAPHS 128
#define N_CLASSES 10
#define BN_EPS 1e-5f

static __device__ __forceinline__ unsigned short f2bf(float f) {
    unsigned u = __float_as_uint(f);
    u += 0x7FFF + ((u >> 16) & 1);   // round-to-nearest-even
    return (unsigned short)(u >> 16);
}

// ---- copy x -> agg (float4) ----
__global__ __launch_bounds__(256) void copy_vec(const f32x4* __restrict__ in,
                                                f32x4* __restrict__ out, int n) {
    int t = blockIdx.x * 256 + threadIdx.x;
    if (t < n) out[t] = in[t];
}

// ---- edge scatter: agg[dst] += feat[src], 32 threads (float4 each) per edge ----
// NOTE: harness delivers integer inputs as int32 (NOT int64 as in the reference).
__global__ __launch_bounds__(256) void scatter_add(const float* __restrict__ feat,
                                                   float* __restrict__ agg,
                                                   const int* __restrict__ ei,
                                                   int nE) {
    int t = blockIdx.x * 256 + threadIdx.x;
    if (t >= nE * 32) return;
    int e = t >> 5, q = t & 31;
    int src = ei[e];
    int dst = ei[nE + e];
    f32x4 v = *(const f32x4*)(feat + (size_t)src * DIM + q * 4);
    float* p = agg + (size_t)dst * DIM + q * 4;
    unsafeAtomicAdd(p + 0, v[0]);
    unsafeAtomicAdd(p + 1, v[1]);
    unsafeAtomicAdd(p + 2, v[2]);
    unsafeAtomicAdd(p + 3, v[3]);
}

// ---- prep: permute W (f32 [128][128], row k, col j) into bf16 B-fragment layout ----
// frag layout: wf[m][ ((n*4+ks)*64 + lane)*8 + e ] = W[k][col],
//   col = n*16 + (lane&15),  k = ks*32 + (lane>>4)*8 + e
__global__ __launch_bounds__(256) void prep_w(const float* __restrict__ W0,
                                              const float* __restrict__ W1,
                                              const float* __restrict__ W2,
                                              const float* __restrict__ W3,
                                              unsigned short* __restrict__ wf) {
    int t = blockIdx.x * 256 + threadIdx.x;
    if (t >= 4 * 16384) return;
    int m = t >> 14, rem = t & 16383;
    int e = rem & 7, lane = (rem >> 3) & 63, fi = rem >> 9;
    int ks = fi & 3, n = fi >> 2;
    int col = n * 16 + (lane & 15);
    int k = ks * 32 + ((lane >> 4) << 3) + e;
    const float* W = (m == 0) ? W0 : (m == 1) ? W1 : (m == 2) ? W2 : W3;
    wf[t] = f2bf(W[k * DIM + col]);
}

// ---- GEMM: out[M,128] = A[M,128] @ W + bias; optional ReLU; optional column stats ----
// block: 256 thr = 4 waves; wave computes 16 rows x 128 cols via 8x4 mfma 16x16x32 bf16
template <bool RELU, bool STATS>
__global__ __launch_bounds__(256) void gemm128(const float* __restrict__ A,
                                               const bf16x8* __restrict__ wfrag,
                                               const float* __restrict__ bias,
                                               float* __restrict__ out,
                                               float* __restrict__ colsum,
                                               float* __restrict__ colsq, int M) {
    int wave = threadIdx.x >> 6;
    int lane = threadIdx.x & 63;
    int r0 = blockIdx.x * 64 + wave * 16;
    int arow = r0 + (lane & 15);
    if (arow >= M) arow = M - 1;
    int kq = lane >> 4;  // 0..3

    // A fragments: row = lane&15, k = kq*8 + e (+32 per kstep)
    bf16x8 af[4];
    const float* Ar = A + (size_t)arow * DIM + kq * 8;
#pragma unroll
    for (int ks = 0; ks < 4; ++ks) {
        f32x4 v0 = *(const f32x4*)(Ar + ks * 32);
        f32x4 v1 = *(const f32x4*)(Ar + ks * 32 + 4);
        bf16x8 a;
#pragma unroll
        for (int i = 0; i < 4; ++i) {
            a[i]     = (short)f2bf(v0[i]);
            a[4 + i] = (short)f2bf(v1[i]);
        }
        af[ks] = a;
    }

    f32x4 acc[8];
#pragma unroll
    for (int n = 0; n < 8; ++n) acc[n] = f32x4{0.f, 0.f, 0.f, 0.f};

#pragma unroll
    for (int n = 0; n < 8; ++n) {
#pragma unroll
        for (int ks = 0; ks < 4; ++ks) {
            bf16x8 b = wfrag[(n * 4 + ks) * 64 + lane];
            acc[n] = __builtin_amdgcn_mfma_f32_16x16x32_bf16(af[ks], b, acc[n], 0, 0, 0);
        }
    }

    // epilogue: D col = lane&15, row = kq*4 + reg  (HW-verified layout)
    int colb = lane & 15;
    int rbase = r0 + kq * 4;
#pragma unroll
    for (int n = 0; n < 8; ++n) {
        int col = n * 16 + colb;
        float b = bias[col];
        float s = 0.f, q = 0.f;
#pragma unroll
        for (int r = 0; r < 4; ++r) {
            int row = rbase + r;
            float v = acc[n][r] + b;
            if (RELU) v = fmaxf(v, 0.f);
            if (row < M) {
                out[(size_t)row * DIM + col] = v;
                if (STATS) { s += v; q += v * v; }
            }
        }
        if (STATS) {
            s += __shfl_xor(s, 16, 64);
            s += __shfl_xor(s, 32, 64);
            q += __shfl_xor(q, 16, 64);
            q += __shfl_xor(q, 32, 64);
            if (kq == 0) {
                unsafeAtomicAdd(&colsum[col], s);
                unsafeAtomicAdd(&colsq[col], q);
            }
        }
    }
}

// ---- BN finalize: scale/shift per column ----
__global__ __launch_bounds__(128) void bn_finalize(const float* __restrict__ colsum,
                                                   const float* __restrict__ colsq,
                                                   const float* __restrict__ g,
                                                   const float* __restrict__ be,
                                                   float* __restrict__ scale,
                                                   float* __restrict__ shift) {
    int c = threadIdx.x;
    const float invN = 1.0f / (float)N_NODES;
    float mu = colsum[c] * invN;
    float var = colsq[c] * invN - mu * mu;
    float rs = rsqrtf(var + BN_EPS) * g[c];
    scale[c] = rs;
    shift[c] = be[c] - mu * rs;
}

// ---- BN apply + ReLU; layer1: write y (in place) + agg2 copy; layer2: pool atomics ----
template <bool POOL>
__global__ __launch_bounds__(256) void bn_apply(const float* __restrict__ h,
                                                const float* __restrict__ scale,
                                                const float* __restrict__ shift,
                                                float* __restrict__ y,
                                                float* __restrict__ agg2,
                                                const int* __restrict__ batch,
                                                float* __restrict__ pooled) {
    int t = blockIdx.x * 256 + threadIdx.x;  // one float4 per thread, N_NODES*32 total
    if (t >= N_NODES * 32) return;
    int c4 = t & 31;
    f32x4 v = ((const f32x4*)h)[t];
    f32x4 sc = ((const f32x4*)scale)[c4];
    f32x4 sh = ((const f32x4*)shift)[c4];
    f32x4 r;
#pragma unroll
    for (int i = 0; i < 4; ++i) r[i] = fmaxf(v[i] * sc[i] + sh[i], 0.f);
    if (!POOL) {
        ((f32x4*)y)[t] = r;
        ((f32x4*)agg2)[t] = r;
    } else {
        int row = t >> 5;
        int gidx = batch[row];
        float* p = pooled + (size_t)gidx * DIM + c4 * 4;
#pragma unroll
        for (int i = 0; i < 4; ++i) unsafeAtomicAdd(p + i, r[i]);
    }
}

// ---- final: out[g][c] = pooled[g] . Wo[:,c] + bo[c] ----
__global__ __launch_bounds__(256) void final_gemm(const float* __restrict__ pooled,
                                                  const float* __restrict__ Wo,
                                                  const float* __restrict__ bo,
                                                  float* __restrict__ out) {
    int t = blockIdx.x * 256 + threadIdx.x;
    if (t >= N_GRAPHS * N_CLASSES) return;
    int g = t / N_CLASSES, c = t - g * N_CLASSES;
    float s = bo[c];
    const float* p = pooled + (size_t)g * DIM;
#pragma unroll 4
    for (int k = 0; k < DIM; ++k) s += p[k] * Wo[k * N_CLASSES + c];
    out[t] = s;
}

extern "C" void kernel_launch(void* const* d_in, const int* in_sizes, int n_in,
                              void* d_out, int out_size, void* d_ws, size_t ws_size,
                              hipStream_t stream) {
    const float* x        = (const float*)d_in[0];
    const int* ei         = (const int*)d_in[1];   // harness: integer -> int32
    const int* batch      = (const int*)d_in[2];   // harness: integer -> int32
    const float* W1a = (const float*)d_in[3];
    const float* b1a = (const float*)d_in[4];
    const float* W1b = (const float*)d_in[5];
    const float* b1b = (const float*)d_in[6];
    const float* g1  = (const float*)d_in[7];
    const float* be1 = (const float*)d_in[8];
    const float* W2a = (const float*)d_in[9];
    const float* b2a = (const float*)d_in[10];
    const float* W2b = (const float*)d_in[11];
    const float* b2b = (const float*)d_in[12];
    const float* g2  = (const float*)d_in[13];
    const float* be2 = (const float*)d_in[14];
    const float* Wo  = (const float*)d_in[15];
    const float* bo  = (const float*)d_in[16];

    char* ws = (char*)d_ws;
    const size_t NB = (size_t)N_NODES * DIM * 4;  // 25,600,000 B
    float* agg = (float*)ws;                       // agg1 then agg2
    float* hA  = (float*)(ws + NB);                // h1 / h3
    float* hB  = (float*)(ws + 2 * NB);            // h2 / y1 / h4
    unsigned short* wfrag = (unsigned short*)(ws + 3 * NB);  // 4 * 16384 bf16
    char* smallb = ws + 3 * NB + 4 * 16384 * 2;
    float* colsum1 = (float*)smallb;
    float* colsq1  = colsum1 + 128;
    float* colsum2 = colsum1 + 256;
    float* colsq2  = colsum1 + 384;
    float* pooled  = colsum1 + 512;                // 128*128
    float* scale1  = pooled + N_GRAPHS * DIM;
    float* shift1  = scale1 + 128;
    float* scale2  = scale1 + 256;
    float* shift2  = scale1 + 384;

    // zero: colsums(4*128) + pooled(16384) floats
    hipMemsetAsync(smallb, 0, (512 + N_GRAPHS * DIM) * 4, stream);

    prep_w<<<256, 256, 0, stream>>>(W1a, W1b, W2a, W2b, wfrag);

    const int nvec = N_NODES * 32;  // float4 count
    copy_vec<<<(nvec + 255) / 256, 256, 0, stream>>>((const f32x4*)x, (f32x4*)agg, nvec);
    scatter_add<<<(N_EDGES * 32) / 256, 256, 0, stream>>>(x, agg, ei, N_EDGES);

    const int gblk = (N_NODES + 63) / 64;
    gemm128<true, false><<<gblk, 256, 0, stream>>>(
        agg, (const bf16x8*)(wfrag + 0 * 16384), b1a, hA, nullptr, nullptr, N_NODES);
    gemm128<false, true><<<gblk, 256, 0, stream>>>(
        hA, (const bf16x8*)(wfrag + 1 * 16384), b1b, hB, colsum1, colsq1, N_NODES);
    bn_finalize<<<1, 128, 0, stream>>>(colsum1, colsq1, g1, be1, scale1, shift1);
    bn_apply<false><<<(nvec + 255) / 256, 256, 0, stream>>>(hB, scale1, shift1, hB, agg,
                                                            nullptr, nullptr);
    scatter_add<<<(N_EDGES * 32) / 256, 256, 0, stream>>>(hB, agg, ei, N_EDGES);

    gemm128<true, false><<<gblk, 256, 0, stream>>>(
        agg, (const bf16x8*)(wfrag + 2 * 16384), b2a, hA, nullptr, nullptr, N_NODES);
    gemm128<false, true><<<gblk, 256, 0, stream>>>(
        hA, (const bf16x8*)(wfrag + 3 * 16384), b2b, hB, colsum2, colsq2, N_NODES);
    bn_finalize<<<1, 128, 0, stream>>>(colsum2, colsq2, g2, be2, scale2, shift2);
    bn_apply<true><<<(nvec + 255) / 256, 256, 0, stream>>>(hB, scale2, shift2, nullptr,
                                                           nullptr, batch, pooled);

    final_gemm<<<(N_GRAPHS * N_CLASSES + 255) / 256, 256, 0, stream>>>(pooled, Wo, bo,
                                                                       (float*)d_out);
}

// Round 3
// 824.588 us; speedup vs baseline: 3.9099x; 3.9099x over previous
//
#include <hip/hip_runtime.h>

typedef __attribute__((ext_vector_type(8))) short bf16x8;
typedef __attribute__((ext_vector_type(4))) float f32x4;
typedef __attribute__((ext_vector_type(2))) float f32x2;

#define N_NODES 50000
#define N_EDGES 800000
#define DIM 128
#define N_GRAPHS 128
#define N_CLASSES 10
#define BN_EPS 1e-5f

static __device__ __forceinline__ unsigned short f2bf(float f) {
    unsigned u = __float_as_uint(f);
    u += 0x7FFF + ((u >> 16) & 1);   // round-to-nearest-even
    return (unsigned short)(u >> 16);
}

// ---- CSR build: histogram of destinations ----
__global__ __launch_bounds__(256) void hist_dst(const int* __restrict__ ei, int* __restrict__ deg) {
    int e = blockIdx.x * 256 + threadIdx.x;
    if (e < N_EDGES) atomicAdd(&deg[ei[N_EDGES + e]], 1);
}

// ---- CSR build: exclusive scan over 50000 degrees (single block of 1024) ----
__global__ __launch_bounds__(1024) void scan_deg(const int* __restrict__ deg,
                                                 int* __restrict__ row_start,
                                                 int* __restrict__ cursor) {
    __shared__ int part[1024];
    const int CH = (N_NODES + 1023) / 1024;  // 49
    int tid = threadIdx.x;
    int base = tid * CH;
    int s = 0;
    for (int i = 0; i < CH; ++i) {
        int idx = base + i;
        if (idx < N_NODES) s += deg[idx];
    }
    part[tid] = s;
    __syncthreads();
    for (int off = 1; off < 1024; off <<= 1) {
        int v = (tid >= off) ? part[tid - off] : 0;
        __syncthreads();
        part[tid] += v;
        __syncthreads();
    }
    int run = (tid == 0) ? 0 : part[tid - 1];
    for (int i = 0; i < CH; ++i) {
        int idx = base + i;
        if (idx < N_NODES) {
            row_start[idx] = run;
            cursor[idx] = run;
            run += deg[idx];
        }
    }
    if (tid == 1023) row_start[N_NODES] = run;
}

// ---- CSR build: scatter sources into per-dst segments ----
__global__ __launch_bounds__(256) void fill_csr(const int* __restrict__ ei,
                                                int* __restrict__ cursor,
                                                int* __restrict__ csr_src) {
    int e = blockIdx.x * 256 + threadIdx.x;
    if (e >= N_EDGES) return;
    int src = ei[e];
    int dst = ei[N_EDGES + e];
    int pos = atomicAdd(&cursor[dst], 1);
    csr_src[pos] = src;
}

// ---- gather-sum aggregation: agg[v] = feat[v] + sum_{e in CSR[v]} feat[src_e] ----
// one wave per node; lane holds float2 (64*2 = 128)
__global__ __launch_bounds__(256) void aggregate(const float* __restrict__ feat,
                                                 float* __restrict__ agg,
                                                 const int* __restrict__ row_start,
                                                 const int* __restrict__ csr_src) {
    int wave = threadIdx.x >> 6, lane = threadIdx.x & 63;
    int v = blockIdx.x * 4 + wave;
    if (v >= N_NODES) return;
    const f32x2* F = (const f32x2*)feat;
    f32x2 acc = F[(size_t)v * 64 + lane];
    int e = row_start[v], end = row_start[v + 1];
    for (; e + 3 < end; e += 4) {
        int s0 = csr_src[e], s1 = csr_src[e + 1], s2 = csr_src[e + 2], s3 = csr_src[e + 3];
        f32x2 a = F[(size_t)s0 * 64 + lane];
        f32x2 b = F[(size_t)s1 * 64 + lane];
        f32x2 c = F[(size_t)s2 * 64 + lane];
        f32x2 d = F[(size_t)s3 * 64 + lane];
        acc += (a + b) + (c + d);
    }
    for (; e < end; ++e) acc += F[(size_t)csr_src[e] * 64 + lane];
    ((f32x2*)agg)[(size_t)v * 64 + lane] = acc;
}

// ---- prep: permute W (f32 [128][128], row k, col j) into bf16 B-fragment layout ----
// frag layout: wf[m][ ((n*4+ks)*64 + lane)*8 + e ] = W[k][col],
//   col = n*16 + (lane&15),  k = ks*32 + (lane>>4)*8 + e
__global__ __launch_bounds__(256) void prep_w(const float* __restrict__ W0,
                                              const float* __restrict__ W1,
                                              const float* __restrict__ W2,
                                              const float* __restrict__ W3,
                                              unsigned short* __restrict__ wf) {
    int t = blockIdx.x * 256 + threadIdx.x;
    if (t >= 4 * 16384) return;
    int m = t >> 14, rem = t & 16383;
    int e = rem & 7, lane = (rem >> 3) & 63, fi = rem >> 9;
    int ks = fi & 3, n = fi >> 2;
    int col = n * 16 + (lane & 15);
    int k = ks * 32 + ((lane >> 4) << 3) + e;
    const float* W = (m == 0) ? W0 : (m == 1) ? W1 : (m == 2) ? W2 : W3;
    wf[t] = f2bf(W[k * DIM + col]);
}

// ---- GEMM: out[M,128] = A[M,128] @ W + bias; optional ReLU; optional column stats ----
template <bool RELU, bool STATS>
__global__ __launch_bounds__(256) void gemm128(const float* __restrict__ A,
                                               const bf16x8* __restrict__ wfrag,
                                               const float* __restrict__ bias,
                                               float* __restrict__ out,
                                               float* __restrict__ colsum,
                                               float* __restrict__ colsq, int M) {
    int wave = threadIdx.x >> 6;
    int lane = threadIdx.x & 63;
    int r0 = blockIdx.x * 64 + wave * 16;
    int arow = r0 + (lane & 15);
    if (arow >= M) arow = M - 1;
    int kq = lane >> 4;  // 0..3

    bf16x8 af[4];
    const float* Ar = A + (size_t)arow * DIM + kq * 8;
#pragma unroll
    for (int ks = 0; ks < 4; ++ks) {
        f32x4 v0 = *(const f32x4*)(Ar + ks * 32);
        f32x4 v1 = *(const f32x4*)(Ar + ks * 32 + 4);
        bf16x8 a;
#pragma unroll
        for (int i = 0; i < 4; ++i) {
            a[i]     = (short)f2bf(v0[i]);
            a[4 + i] = (short)f2bf(v1[i]);
        }
        af[ks] = a;
    }

    f32x4 acc[8];
#pragma unroll
    for (int n = 0; n < 8; ++n) acc[n] = f32x4{0.f, 0.f, 0.f, 0.f};

#pragma unroll
    for (int n = 0; n < 8; ++n) {
#pragma unroll
        for (int ks = 0; ks < 4; ++ks) {
            bf16x8 b = wfrag[(n * 4 + ks) * 64 + lane];
            acc[n] = __builtin_amdgcn_mfma_f32_16x16x32_bf16(af[ks], b, acc[n], 0, 0, 0);
        }
    }

    int colb = lane & 15;
    int rbase = r0 + kq * 4;
#pragma unroll
    for (int n = 0; n < 8; ++n) {
        int col = n * 16 + colb;
        float b = bias[col];
        float s = 0.f, q = 0.f;
#pragma unroll
        for (int r = 0; r < 4; ++r) {
            int row = rbase + r;
            float v = acc[n][r] + b;
            if (RELU) v = fmaxf(v, 0.f);
            if (row < M) {
                out[(size_t)row * DIM + col] = v;
                if (STATS) { s += v; q += v * v; }
            }
        }
        if (STATS) {
            s += __shfl_xor(s, 16, 64);
            s += __shfl_xor(s, 32, 64);
            q += __shfl_xor(q, 16, 64);
            q += __shfl_xor(q, 32, 64);
            if (kq == 0) {
                unsafeAtomicAdd(&colsum[col], s);
                unsafeAtomicAdd(&colsq[col], q);
            }
        }
    }
}

// ---- BN finalize ----
__global__ __launch_bounds__(128) void bn_finalize(const float* __restrict__ colsum,
                                                   const float* __restrict__ colsq,
                                                   const float* __restrict__ g,
                                                   const float* __restrict__ be,
                                                   float* __restrict__ scale,
                                                   float* __restrict__ shift) {
    int c = threadIdx.x;
    const float invN = 1.0f / (float)N_NODES;
    float mu = colsum[c] * invN;
    float var = colsq[c] * invN - mu * mu;
    float rs = rsqrtf(var + BN_EPS) * g[c];
    scale[c] = rs;
    shift[c] = be[c] - mu * rs;
}

// ---- BN apply + ReLU; POOL=false: write y in place; POOL=true: pool atomics ----
template <bool POOL>
__global__ __launch_bounds__(256) void bn_apply(const float* __restrict__ h,
                                                const float* __restrict__ scale,
                                                const float* __restrict__ shift,
                                                float* __restrict__ y,
                                                const int* __restrict__ batch,
                                                float* __restrict__ pooled) {
    int t = blockIdx.x * 256 + threadIdx.x;  // one float4 per thread
    if (t >= N_NODES * 32) return;
    int c4 = t & 31;
    f32x4 v = ((const f32x4*)h)[t];
    f32x4 sc = ((const f32x4*)scale)[c4];
    f32x4 sh = ((const f32x4*)shift)[c4];
    f32x4 r;
#pragma unroll
    for (int i = 0; i < 4; ++i) r[i] = fmaxf(v[i] * sc[i] + sh[i], 0.f);
    if (!POOL) {
        ((f32x4*)y)[t] = r;
    } else {
        int row = t >> 5;
        int gidx = batch[row];
        float* p = pooled + (size_t)gidx * DIM + c4 * 4;
#pragma unroll
        for (int i = 0; i < 4; ++i) unsafeAtomicAdd(p + i, r[i]);
    }
}

// ---- final: out[g][c] = pooled[g] . Wo[:,c] + bo[c] ----
__global__ __launch_bounds__(256) void final_gemm(const float* __restrict__ pooled,
                                                  const float* __restrict__ Wo,
                                                  const float* __restrict__ bo,
                                                  float* __restrict__ out) {
    int t = blockIdx.x * 256 + threadIdx.x;
    if (t >= N_GRAPHS * N_CLASSES) return;
    int g = t / N_CLASSES, c = t - g * N_CLASSES;
    float s = bo[c];
    const float* p = pooled + (size_t)g * DIM;
#pragma unroll 4
    for (int k = 0; k < DIM; ++k) s += p[k] * Wo[k * N_CLASSES + c];
    out[t] = s;
}

extern "C" void kernel_launch(void* const* d_in, const int* in_sizes, int n_in,
                              void* d_out, int out_size, void* d_ws, size_t ws_size,
                              hipStream_t stream) {
    const float* x   = (const float*)d_in[0];
    const int* ei    = (const int*)d_in[1];   // harness: integer -> int32
    const int* batch = (const int*)d_in[2];
    const float* W1a = (const float*)d_in[3];
    const float* b1a = (const float*)d_in[4];
    const float* W1b = (const float*)d_in[5];
    const float* b1b = (const float*)d_in[6];
    const float* g1  = (const float*)d_in[7];
    const float* be1 = (const float*)d_in[8];
    const float* W2a = (const float*)d_in[9];
    const float* b2a = (const float*)d_in[10];
    const float* W2b = (const float*)d_in[11];
    const float* b2b = (const float*)d_in[12];
    const float* g2  = (const float*)d_in[13];
    const float* be2 = (const float*)d_in[14];
    const float* Wo  = (const float*)d_in[15];
    const float* bo  = (const float*)d_in[16];

    char* ws = (char*)d_ws;
    const size_t NB = (size_t)N_NODES * DIM * 4;  // 25,600,000 B
    float* agg = (float*)ws;
    float* hA  = (float*)(ws + NB);
    float* hB  = (float*)(ws + 2 * NB);
    unsigned short* wfrag = (unsigned short*)(ws + 3 * NB);  // 4*16384 bf16 = 128 KB
    char* smallb = ws + 3 * NB + 4 * 16384 * 2;
    float* colsum1 = (float*)smallb;
    float* colsq1  = colsum1 + 128;
    float* colsum2 = colsum1 + 256;
    float* colsq2  = colsum1 + 384;
    float* pooled  = colsum1 + 512;                // 128*128
    float* scale1  = pooled + N_GRAPHS * DIM;
    float* shift1  = scale1 + 128;
    float* scale2  = scale1 + 256;
    float* shift2  = scale1 + 384;
    int* deg       = (int*)(shift2 + 128);
    int* row_start = deg + N_NODES;            // N_NODES+1
    int* cursor    = row_start + N_NODES + 1;
    int* csr_src   = cursor + N_NODES;         // N_EDGES

    // zero: colsums(512) + pooled(16384) floats, and deg(50000) ints
    hipMemsetAsync(smallb, 0, (512 + N_GRAPHS * DIM) * 4, stream);
    hipMemsetAsync(deg, 0, N_NODES * 4, stream);

    prep_w<<<256, 256, 0, stream>>>(W1a, W1b, W2a, W2b, wfrag);

    // CSR build (per call; deterministic set, order-free sums)
    const int eblk = (N_EDGES + 255) / 256;
    hist_dst<<<eblk, 256, 0, stream>>>(ei, deg);
    scan_deg<<<1, 1024, 0, stream>>>(deg, row_start, cursor);
    fill_csr<<<eblk, 256, 0, stream>>>(ei, cursor, csr_src);

    const int ablk = (N_NODES + 3) / 4;
    const int gblk = (N_NODES + 63) / 64;
    const int nvec = N_NODES * 32;

    // layer 1
    aggregate<<<ablk, 256, 0, stream>>>(x, agg, row_start, csr_src);
    gemm128<true, false><<<gblk, 256, 0, stream>>>(
        agg, (const bf16x8*)(wfrag + 0 * 16384), b1a, hA, nullptr, nullptr, N_NODES);
    gemm128<false, true><<<gblk, 256, 0, stream>>>(
        hA, (const bf16x8*)(wfrag + 1 * 16384), b1b, hB, colsum1, colsq1, N_NODES);
    bn_finalize<<<1, 128, 0, stream>>>(colsum1, colsq1, g1, be1, scale1, shift1);
    bn_apply<false><<<(nvec + 255) / 256, 256, 0, stream>>>(hB, scale1, shift1, hB,
                                                            nullptr, nullptr);

    // layer 2
    aggregate<<<ablk, 256, 0, stream>>>(hB, agg, row_start, csr_src);
    gemm128<true, false><<<gblk, 256, 0, stream>>>(
        agg, (const bf16x8*)(wfrag + 2 * 16384), b2a, hA, nullptr, nullptr, N_NODES);
    gemm128<false, true><<<gblk, 256, 0, stream>>>(
        hA, (const bf16x8*)(wfrag + 3 * 16384), b2b, hB, colsum2, colsq2, N_NODES);
    bn_finalize<<<1, 128, 0, stream>>>(colsum2, colsq2, g2, be2, scale2, shift2);
    bn_apply<true><<<(nvec + 255) / 256, 256, 0, stream>>>(hB, scale2, shift2, nullptr,
                                                           batch, pooled);

    final_gemm<<<(N_GRAPHS * N_CLASSES + 255) / 256, 256, 0, stream>>>(pooled, Wo, bo,
                                                                       (float*)d_out);
}

// Round 4
// 726.908 us; speedup vs baseline: 4.4353x; 1.1344x over previous
//
#include <hip/hip_runtime.h>

typedef __attribute__((ext_vector_type(8))) short bf16x8;
typedef __attribute__((ext_vector_type(4))) float f32x4;
typedef __attribute__((ext_vector_type(2))) float f32x2;

#define N_NODES 50000
#define N_EDGES 800000
#define DIM 128
#define N_GRAPHS 128
#define N_CLASSES 10
#define BN_EPS 1e-5f

static __device__ __forceinline__ unsigned short f2bf(float f) {
    unsigned u = __float_as_uint(f);
    u += 0x7FFF + ((u >> 16) & 1);   // round-to-nearest-even
    return (unsigned short)(u >> 16);
}

// ---- CSR build: histogram of destinations ----
__global__ __launch_bounds__(256) void hist_dst(const int* __restrict__ ei, int* __restrict__ deg) {
    int e = blockIdx.x * 256 + threadIdx.x;
    if (e < N_EDGES) atomicAdd(&deg[ei[N_EDGES + e]], 1);
}

// ---- CSR build: exclusive scan over 50000 degrees (single block of 1024) ----
__global__ __launch_bounds__(1024) void scan_deg(const int* __restrict__ deg,
                                                 int* __restrict__ row_start,
                                                 int* __restrict__ cursor) {
    __shared__ int part[1024];
    const int CH = (N_NODES + 1023) / 1024;  // 49
    int tid = threadIdx.x;
    int base = tid * CH;
    int s = 0;
    for (int i = 0; i < CH; ++i) {
        int idx = base + i;
        if (idx < N_NODES) s += deg[idx];
    }
    part[tid] = s;
    __syncthreads();
    for (int off = 1; off < 1024; off <<= 1) {
        int v = (tid >= off) ? part[tid - off] : 0;
        __syncthreads();
        part[tid] += v;
        __syncthreads();
    }
    int run = (tid == 0) ? 0 : part[tid - 1];
    for (int i = 0; i < CH; ++i) {
        int idx = base + i;
        if (idx < N_NODES) {
            row_start[idx] = run;
            cursor[idx] = run;
            run += deg[idx];
        }
    }
    if (tid == 1023) row_start[N_NODES] = run;
}

// ---- CSR build: scatter sources into per-dst segments ----
__global__ __launch_bounds__(256) void fill_csr(const int* __restrict__ ei,
                                                int* __restrict__ cursor,
                                                int* __restrict__ csr_src) {
    int e = blockIdx.x * 256 + threadIdx.x;
    if (e >= N_EDGES) return;
    int src = ei[e];
    int dst = ei[N_EDGES + e];
    int pos = atomicAdd(&cursor[dst], 1);
    csr_src[pos] = src;
}

// ---- graph segment starts via binary search (batch is sorted) ----
__global__ __launch_bounds__(256) void graph_starts(const int* __restrict__ batch,
                                                    int* __restrict__ gs) {
    int g = blockIdx.x * 256 + threadIdx.x;
    if (g > N_GRAPHS) return;
    int lo = 0, hi = N_NODES;
    while (lo < hi) {
        int mid = (lo + hi) >> 1;
        if (batch[mid] < g) lo = mid + 1; else hi = mid;
    }
    gs[g] = lo;
}

// ---- gather-sum aggregation: agg[v] = feat[v] + sum_{e in CSR[v]} feat[src_e] ----
// one wave per node; lane holds float2 (64*2 = 128)
__global__ __launch_bounds__(256) void aggregate(const float* __restrict__ feat,
                                                 float* __restrict__ agg,
                                                 const int* __restrict__ row_start,
                                                 const int* __restrict__ csr_src) {
    int wave = threadIdx.x >> 6, lane = threadIdx.x & 63;
    int v = blockIdx.x * 4 + wave;
    if (v >= N_NODES) return;
    const f32x2* F = (const f32x2*)feat;
    f32x2 acc = F[(size_t)v * 64 + lane];
    int e = row_start[v], end = row_start[v + 1];
    for (; e + 3 < end; e += 4) {
        int s0 = csr_src[e], s1 = csr_src[e + 1], s2 = csr_src[e + 2], s3 = csr_src[e + 3];
        f32x2 a = F[(size_t)s0 * 64 + lane];
        f32x2 b = F[(size_t)s1 * 64 + lane];
        f32x2 c = F[(size_t)s2 * 64 + lane];
        f32x2 d = F[(size_t)s3 * 64 + lane];
        acc += (a + b) + (c + d);
    }
    for (; e < end; ++e) acc += F[(size_t)csr_src[e] * 64 + lane];
    ((f32x2*)agg)[(size_t)v * 64 + lane] = acc;
}

// ---- prep: permute W (f32 [128][128], row k, col j) into bf16 B-fragment layout ----
// frag layout: wf[m][ ((n*4+ks)*64 + lane)*8 + e ] = W[k][col],
//   col = n*16 + (lane&15),  k = ks*32 + (lane>>4)*8 + e
__global__ __launch_bounds__(256) void prep_w(const float* __restrict__ W0,
                                              const float* __restrict__ W1,
                                              const float* __restrict__ W2,
                                              const float* __restrict__ W3,
                                              unsigned short* __restrict__ wf) {
    int t = blockIdx.x * 256 + threadIdx.x;
    if (t >= 4 * 16384) return;
    int m = t >> 14, rem = t & 16383;
    int e = rem & 7, lane = (rem >> 3) & 63, fi = rem >> 9;
    int ks = fi & 3, n = fi >> 2;
    int col = n * 16 + (lane & 15);
    int k = ks * 32 + ((lane >> 4) << 3) + e;
    const float* W = (m == 0) ? W0 : (m == 1) ? W1 : (m == 2) ? W2 : W3;
    wf[t] = f2bf(W[k * DIM + col]);
}

// ---- GEMM: out[M,128] = A[M,128] @ W + bias; optional ReLU; optional column stats ----
template <bool RELU, bool STATS>
__global__ __launch_bounds__(256) void gemm128(const float* __restrict__ A,
                                               const bf16x8* __restrict__ wfrag,
                                               const float* __restrict__ bias,
                                               float* __restrict__ out,
                                               float* __restrict__ colsum,
                                               float* __restrict__ colsq, int M) {
    int wave = threadIdx.x >> 6;
    int lane = threadIdx.x & 63;
    int r0 = blockIdx.x * 64 + wave * 16;
    int arow = r0 + (lane & 15);
    if (arow >= M) arow = M - 1;
    int kq = lane >> 4;  // 0..3

    bf16x8 af[4];
    const float* Ar = A + (size_t)arow * DIM + kq * 8;
#pragma unroll
    for (int ks = 0; ks < 4; ++ks) {
        f32x4 v0 = *(const f32x4*)(Ar + ks * 32);
        f32x4 v1 = *(const f32x4*)(Ar + ks * 32 + 4);
        bf16x8 a;
#pragma unroll
        for (int i = 0; i < 4; ++i) {
            a[i]     = (short)f2bf(v0[i]);
            a[4 + i] = (short)f2bf(v1[i]);
        }
        af[ks] = a;
    }

    f32x4 acc[8];
#pragma unroll
    for (int n = 0; n < 8; ++n) acc[n] = f32x4{0.f, 0.f, 0.f, 0.f};

#pragma unroll
    for (int n = 0; n < 8; ++n) {
#pragma unroll
        for (int ks = 0; ks < 4; ++ks) {
            bf16x8 b = wfrag[(n * 4 + ks) * 64 + lane];
            acc[n] = __builtin_amdgcn_mfma_f32_16x16x32_bf16(af[ks], b, acc[n], 0, 0, 0);
        }
    }

    int colb = lane & 15;
    int rbase = r0 + kq * 4;
#pragma unroll
    for (int n = 0; n < 8; ++n) {
        int col = n * 16 + colb;
        float b = bias[col];
        float s = 0.f, q = 0.f;
#pragma unroll
        for (int r = 0; r < 4; ++r) {
            int row = rbase + r;
            float v = acc[n][r] + b;
            if (RELU) v = fmaxf(v, 0.f);
            if (row < M) {
                out[(size_t)row * DIM + col] = v;
                if (STATS) { s += v; q += v * v; }
            }
        }
        if (STATS) {
            s += __shfl_xor(s, 16, 64);
            s += __shfl_xor(s, 32, 64);
            q += __shfl_xor(q, 16, 64);
            q += __shfl_xor(q, 32, 64);
            if (kq == 0) {
                unsafeAtomicAdd(&colsum[col], s);
                unsafeAtomicAdd(&colsq[col], q);
            }
        }
    }
}

// ---- BN finalize ----
__global__ __launch_bounds__(128) void bn_finalize(const float* __restrict__ colsum,
                                                   const float* __restrict__ colsq,
                                                   const float* __restrict__ g,
                                                   const float* __restrict__ be,
                                                   float* __restrict__ scale,
                                                   float* __restrict__ shift) {
    int c = threadIdx.x;
    const float invN = 1.0f / (float)N_NODES;
    float mu = colsum[c] * invN;
    float var = colsq[c] * invN - mu * mu;
    float rs = rsqrtf(var + BN_EPS) * g[c];
    scale[c] = rs;
    shift[c] = be[c] - mu * rs;
}

// ---- BN apply + ReLU (layer 1): y = relu(h*scale+shift), in place ----
__global__ __launch_bounds__(256) void bn_apply(const float* __restrict__ h,
                                                const float* __restrict__ scale,
                                                const float* __restrict__ shift,
                                                float* __restrict__ y) {
    int t = blockIdx.x * 256 + threadIdx.x;  // one float4 per thread
    if (t >= N_NODES * 32) return;
    int c4 = t & 31;
    f32x4 v = ((const f32x4*)h)[t];
    f32x4 sc = ((const f32x4*)scale)[c4];
    f32x4 sh = ((const f32x4*)shift)[c4];
    f32x4 r;
#pragma unroll
    for (int i = 0; i < 4; ++i) r[i] = fmaxf(v[i] * sc[i] + sh[i], 0.f);
    ((f32x4*)y)[t] = r;
}

// ---- BN apply + ReLU + segmented pool (layer 2): one block per graph, NO atomics ----
__global__ __launch_bounds__(256) void bn_pool(const float* __restrict__ h,
                                               const float* __restrict__ scale,
                                               const float* __restrict__ shift,
                                               const int* __restrict__ gs,
                                               float* __restrict__ pooled) {
    int g = blockIdx.x;
    int t = threadIdx.x;
    int c4 = t & 31;   // float4 column group
    int rs = t >> 5;   // row stream 0..7
    int r0 = gs[g], r1 = gs[g + 1];
    f32x4 sc = ((const f32x4*)scale)[c4];
    f32x4 sh = ((const f32x4*)shift)[c4];
    f32x4 acc = f32x4{0.f, 0.f, 0.f, 0.f};
    for (int r = r0 + rs; r < r1; r += 8) {
        f32x4 v = ((const f32x4*)h)[(size_t)r * 32 + c4];
#pragma unroll
        for (int i = 0; i < 4; ++i) acc[i] += fmaxf(v[i] * sc[i] + sh[i], 0.f);
    }
    __shared__ f32x4 red[256];
    red[t] = acc;
    __syncthreads();
#pragma unroll
    for (int off = 128; off >= 32; off >>= 1) {
        if (t < off) red[t] += red[t + off];
        __syncthreads();
    }
    if (t < 32) ((f32x4*)pooled)[g * 32 + c4] = red[t];
}

// ---- final: out[g][c] = pooled[g] . Wo[:,c] + bo[c] ----
__global__ __launch_bounds__(256) void final_gemm(const float* __restrict__ pooled,
                                                  const float* __restrict__ Wo,
                                                  const float* __restrict__ bo,
                                                  float* __restrict__ out) {
    int t = blockIdx.x * 256 + threadIdx.x;
    if (t >= N_GRAPHS * N_CLASSES) return;
    int g = t / N_CLASSES, c = t - g * N_CLASSES;
    float s = bo[c];
    const float* p = pooled + (size_t)g * DIM;
#pragma unroll 4
    for (int k = 0; k < DIM; ++k) s += p[k] * Wo[k * N_CLASSES + c];
    out[t] = s;
}

extern "C" void kernel_launch(void* const* d_in, const int* in_sizes, int n_in,
                              void* d_out, int out_size, void* d_ws, size_t ws_size,
                              hipStream_t stream) {
    const float* x   = (const float*)d_in[0];
    const int* ei    = (const int*)d_in[1];   // harness: integer -> int32
    const int* batch = (const int*)d_in[2];
    const float* W1a = (const float*)d_in[3];
    const float* b1a = (const float*)d_in[4];
    const float* W1b = (const float*)d_in[5];
    const float* b1b = (const float*)d_in[6];
    const float* g1  = (const float*)d_in[7];
    const float* be1 = (const float*)d_in[8];
    const float* W2a = (const float*)d_in[9];
    const float* b2a = (const float*)d_in[10];
    const float* W2b = (const float*)d_in[11];
    const float* b2b = (const float*)d_in[12];
    const float* g2  = (const float*)d_in[13];
    const float* be2 = (const float*)d_in[14];
    const float* Wo  = (const float*)d_in[15];
    const float* bo  = (const float*)d_in[16];

    char* ws = (char*)d_ws;
    const size_t NB = (size_t)N_NODES * DIM * 4;  // 25,600,000 B
    float* agg = (float*)ws;
    float* hA  = (float*)(ws + NB);
    float* hB  = (float*)(ws + 2 * NB);
    unsigned short* wfrag = (unsigned short*)(ws + 3 * NB);  // 4*16384 bf16 = 128 KB
    char* smallb = ws + 3 * NB + 4 * 16384 * 2;
    float* colsum1 = (float*)smallb;
    float* colsq1  = colsum1 + 128;
    float* colsum2 = colsum1 + 256;
    float* colsq2  = colsum1 + 384;
    float* pooled  = colsum1 + 512;                // 128*128
    float* scale1  = pooled + N_GRAPHS * DIM;
    float* shift1  = scale1 + 128;
    float* scale2  = scale1 + 256;
    float* shift2  = scale1 + 384;
    int* gs        = (int*)(shift2 + 128);     // N_GRAPHS+1
    int* deg       = gs + N_GRAPHS + 1;
    int* row_start = deg + N_NODES;            // N_NODES+1
    int* cursor    = row_start + N_NODES + 1;
    int* csr_src   = cursor + N_NODES;         // N_EDGES

    // zero: colsums (4*128 floats); pooled is fully overwritten by bn_pool
    hipMemsetAsync(smallb, 0, 512 * 4, stream);
    hipMemsetAsync(deg, 0, N_NODES * 4, stream);

    prep_w<<<256, 256, 0, stream>>>(W1a, W1b, W2a, W2b, wfrag);
    graph_starts<<<1, 256, 0, stream>>>(batch, gs);

    // CSR build (per call; deterministic set, order-free sums)
    const int eblk = (N_EDGES + 255) / 256;
    hist_dst<<<eblk, 256, 0, stream>>>(ei, deg);
    scan_deg<<<1, 1024, 0, stream>>>(deg, row_start, cursor);
    fill_csr<<<eblk, 256, 0, stream>>>(ei, cursor, csr_src);

    const int ablk = (N_NODES + 3) / 4;
    const int gblk = (N_NODES + 63) / 64;
    const int nvec = N_NODES * 32;

    // layer 1
    aggregate<<<ablk, 256, 0, stream>>>(x, agg, row_start, csr_src);
    gemm128<true, false><<<gblk, 256, 0, stream>>>(
        agg, (const bf16x8*)(wfrag + 0 * 16384), b1a, hA, nullptr, nullptr, N_NODES);
    gemm128<false, true><<<gblk, 256, 0, stream>>>(
        hA, (const bf16x8*)(wfrag + 1 * 16384), b1b, hB, colsum1, colsq1, N_NODES);
    bn_finalize<<<1, 128, 0, stream>>>(colsum1, colsq1, g1, be1, scale1, shift1);
    bn_apply<<<(nvec + 255) / 256, 256, 0, stream>>>(hB, scale1, shift1, hB);

    // layer 2
    aggregate<<<ablk, 256, 0, stream>>>(hB, agg, row_start, csr_src);
    gemm128<true, false><<<gblk, 256, 0, stream>>>(
        agg, (const bf16x8*)(wfrag + 2 * 16384), b2a, hA, nullptr, nullptr, N_NODES);
    gemm128<false, true><<<gblk, 256, 0, stream>>>(
        hA, (const bf16x8*)(wfrag + 3 * 16384), b2b, hB, colsum2, colsq2, N_NODES);
    bn_finalize<<<1, 128, 0, stream>>>(colsum2, colsq2, g2, be2, scale2, shift2);
    bn_pool<<<N_GRAPHS, 256, 0, stream>>>(hB, scale2, shift2, gs, pooled);

    final_gemm<<<(N_GRAPHS * N_CLASSES + 255) / 256, 256, 0, stream>>>(pooled, Wo, bo,
                                                                       (float*)d_out);
}

// Round 5
// 661.923 us; speedup vs baseline: 4.8707x; 1.0982x over previous
//
#include <hip/hip_runtime.h>

typedef __attribute__((ext_vector_type(8))) short bf16x8;
typedef __attribute__((ext_vector_type(4))) float f32x4;
typedef __attribute__((ext_vector_type(2))) float f32x2;

#define N_NODES 50000
#define N_EDGES 800000
#define DIM 128
#define N_GRAPHS 128
#define N_CLASSES 10
#define BN_EPS 1e-5f

static __device__ __forceinline__ unsigned short f2bf(float f) {
    unsigned u = __float_as_uint(f);
    u += 0x7FFF + ((u >> 16) & 1);   // round-to-nearest-even
    return (unsigned short)(u >> 16);
}

// ---- CSR build: histogram of destinations ----
__global__ __launch_bounds__(256) void hist_dst(const int* __restrict__ ei, int* __restrict__ deg) {
    int e = blockIdx.x * 256 + threadIdx.x;
    if (e < N_EDGES) atomicAdd(&deg[ei[N_EDGES + e]], 1);
}

// ---- CSR build: exclusive scan over 50000 degrees (single block of 1024) ----
__global__ __launch_bounds__(1024) void scan_deg(const int* __restrict__ deg,
                                                 int* __restrict__ row_start,
                                                 int* __restrict__ cursor) {
    __shared__ int part[1024];
    const int CH = (N_NODES + 1023) / 1024;  // 49
    int tid = threadIdx.x;
    int base = tid * CH;
    int s = 0;
    for (int i = 0; i < CH; ++i) {
        int idx = base + i;
        if (idx < N_NODES) s += deg[idx];
    }
    part[tid] = s;
    __syncthreads();
    for (int off = 1; off < 1024; off <<= 1) {
        int v = (tid >= off) ? part[tid - off] : 0;
        __syncthreads();
        part[tid] += v;
        __syncthreads();
    }
    int run = (tid == 0) ? 0 : part[tid - 1];
    for (int i = 0; i < CH; ++i) {
        int idx = base + i;
        if (idx < N_NODES) {
            row_start[idx] = run;
            cursor[idx] = run;
            run += deg[idx];
        }
    }
    if (tid == 1023) row_start[N_NODES] = run;
}

// ---- CSR build: scatter sources into per-dst segments ----
__global__ __launch_bounds__(256) void fill_csr(const int* __restrict__ ei,
                                                int* __restrict__ cursor,
                                                int* __restrict__ csr_src) {
    int e = blockIdx.x * 256 + threadIdx.x;
    if (e >= N_EDGES) return;
    int src = ei[e];
    int dst = ei[N_EDGES + e];
    int pos = atomicAdd(&cursor[dst], 1);
    csr_src[pos] = src;
}

// ---- graph segment starts via binary search (batch is sorted) ----
__global__ __launch_bounds__(256) void graph_starts(const int* __restrict__ batch,
                                                    int* __restrict__ gs) {
    int g = blockIdx.x * 256 + threadIdx.x;
    if (g > N_GRAPHS) return;
    int lo = 0, hi = N_NODES;
    while (lo < hi) {
        int mid = (lo + hi) >> 1;
        if (batch[mid] < g) lo = mid + 1; else hi = mid;
    }
    gs[g] = lo;
}

// ---- gather-sum aggregation; BN=true applies relu(f*scale+shift) per gathered row ----
// agg[v] = t(feat[v]) + sum_{e in CSR[v]} t(feat[src_e]),  t = BN? relu(bn(.)) : identity
template <bool BN>
__global__ __launch_bounds__(256) void aggregate(const float* __restrict__ feat,
                                                 float* __restrict__ agg,
                                                 const int* __restrict__ row_start,
                                                 const int* __restrict__ csr_src,
                                                 const float* __restrict__ scale,
                                                 const float* __restrict__ shift) {
    int wave = threadIdx.x >> 6, lane = threadIdx.x & 63;
    int v = blockIdx.x * 4 + wave;
    if (v >= N_NODES) return;
    const f32x2* F = (const f32x2*)feat;
    f32x2 sc, sh;
    if (BN) {
        sc = ((const f32x2*)scale)[lane];
        sh = ((const f32x2*)shift)[lane];
    }
    f32x2 t = F[(size_t)v * 64 + lane];
    f32x2 acc;
    if (BN) {
        acc[0] = fmaxf(t[0] * sc[0] + sh[0], 0.f);
        acc[1] = fmaxf(t[1] * sc[1] + sh[1], 0.f);
    } else {
        acc = t;
    }
    int e = row_start[v], end = row_start[v + 1];
    for (; e + 3 < end; e += 4) {
        int s0 = csr_src[e], s1 = csr_src[e + 1], s2 = csr_src[e + 2], s3 = csr_src[e + 3];
        f32x2 a = F[(size_t)s0 * 64 + lane];
        f32x2 b = F[(size_t)s1 * 64 + lane];
        f32x2 c = F[(size_t)s2 * 64 + lane];
        f32x2 d = F[(size_t)s3 * 64 + lane];
        if (BN) {
#pragma unroll
            for (int i = 0; i < 2; ++i) {
                a[i] = fmaxf(a[i] * sc[i] + sh[i], 0.f);
                b[i] = fmaxf(b[i] * sc[i] + sh[i], 0.f);
                c[i] = fmaxf(c[i] * sc[i] + sh[i], 0.f);
                d[i] = fmaxf(d[i] * sc[i] + sh[i], 0.f);
            }
        }
        acc += (a + b) + (c + d);
    }
    for (; e < end; ++e) {
        f32x2 a = F[(size_t)csr_src[e] * 64 + lane];
        if (BN) {
#pragma unroll
            for (int i = 0; i < 2; ++i) a[i] = fmaxf(a[i] * sc[i] + sh[i], 0.f);
        }
        acc += a;
    }
    ((f32x2*)agg)[(size_t)v * 64 + lane] = acc;
}

// ---- prep: permute W (f32 [128][128], row k, col j) into bf16 B-fragment layout ----
// frag layout: wf[m][ ((n*4+ks)*64 + lane)*8 + e ] = W[k][col],
//   col = n*16 + (lane&15),  k = ks*32 + (lane>>4)*8 + e
__global__ __launch_bounds__(256) void prep_w(const float* __restrict__ W0,
                                              const float* __restrict__ W1,
                                              const float* __restrict__ W2,
                                              const float* __restrict__ W3,
                                              unsigned short* __restrict__ wf) {
    int t = blockIdx.x * 256 + threadIdx.x;
    if (t >= 4 * 16384) return;
    int m = t >> 14, rem = t & 16383;
    int e = rem & 7, lane = (rem >> 3) & 63, fi = rem >> 9;
    int ks = fi & 3, n = fi >> 2;
    int col = n * 16 + (lane & 15);
    int k = ks * 32 + ((lane >> 4) << 3) + e;
    const float* W = (m == 0) ? W0 : (m == 1) ? W1 : (m == 2) ? W2 : W3;
    wf[t] = f2bf(W[k * DIM + col]);
}

// ---- GEMM: out[M, 64-col half] = A[M,128] @ W + bias; latency-optimized ----
// grid (rowTiles, 2); wave = 16 rows x 64 cols; ALL loads prefetched before MFMA
template <bool RELU, bool STATS>
__global__ __launch_bounds__(256, 2) void gemm64(const float* __restrict__ A,
                                                 const bf16x8* __restrict__ wfrag,
                                                 const float* __restrict__ bias,
                                                 float* __restrict__ out,
                                                 float* __restrict__ colsum,
                                                 float* __restrict__ colsq, int M) {
    int wave = threadIdx.x >> 6;
    int lane = threadIdx.x & 63;
    int r0 = blockIdx.x * 64 + wave * 16;
    int nh = blockIdx.y;               // column half: cols [nh*64, nh*64+64)
    int arow = r0 + (lane & 15);
    if (arow >= M) arow = M - 1;
    int kq = lane >> 4;  // 0..3

    // prefetch all 16 B fragments (independent 16B loads)
    bf16x8 bf[16];
#pragma unroll
    for (int i = 0; i < 16; ++i) bf[i] = wfrag[(nh * 16 + i) * 64 + lane];

    // prefetch all 8 A vectors
    const float* Ar = A + (size_t)arow * DIM + kq * 8;
    f32x4 a0[4], a1[4];
#pragma unroll
    for (int ks = 0; ks < 4; ++ks) {
        a0[ks] = *(const f32x4*)(Ar + ks * 32);
        a1[ks] = *(const f32x4*)(Ar + ks * 32 + 4);
    }

    // convert A to bf16 fragments: row = lane&15, k = kq*8 + e (+32 per ks)
    bf16x8 af[4];
#pragma unroll
    for (int ks = 0; ks < 4; ++ks) {
        bf16x8 a;
#pragma unroll
        for (int i = 0; i < 4; ++i) {
            a[i]     = (short)f2bf(a0[ks][i]);
            a[4 + i] = (short)f2bf(a1[ks][i]);
        }
        af[ks] = a;
    }

    f32x4 acc[4];
#pragma unroll
    for (int j = 0; j < 4; ++j) acc[j] = f32x4{0.f, 0.f, 0.f, 0.f};

#pragma unroll
    for (int j = 0; j < 4; ++j) {
#pragma unroll
        for (int ks = 0; ks < 4; ++ks) {
            acc[j] = __builtin_amdgcn_mfma_f32_16x16x32_bf16(af[ks], bf[j * 4 + ks],
                                                             acc[j], 0, 0, 0);
        }
    }

    // epilogue: D col = lane&15, row = kq*4 + reg (HW-verified layout)
    int colb = lane & 15;
    int rbase = r0 + kq * 4;
#pragma unroll
    for (int j = 0; j < 4; ++j) {
        int col = nh * 64 + j * 16 + colb;
        float b = bias[col];
        float s = 0.f, q = 0.f;
#pragma unroll
        for (int r = 0; r < 4; ++r) {
            int row = rbase + r;
            float v = acc[j][r] + b;
            if (RELU) v = fmaxf(v, 0.f);
            if (row < M) {
                out[(size_t)row * DIM + col] = v;
                if (STATS) { s += v; q += v * v; }
            }
        }
        if (STATS) {
            s += __shfl_xor(s, 16, 64);
            s += __shfl_xor(s, 32, 64);
            q += __shfl_xor(q, 16, 64);
            q += __shfl_xor(q, 32, 64);
            if (kq == 0) {
                unsafeAtomicAdd(&colsum[col], s);
                unsafeAtomicAdd(&colsq[col], q);
            }
        }
    }
}

// ---- BN finalize ----
__global__ __launch_bounds__(128) void bn_finalize(const float* __restrict__ colsum,
                                                   const float* __restrict__ colsq,
                                                   const float* __restrict__ g,
                                                   const float* __restrict__ be,
                                                   float* __restrict__ scale,
                                                   float* __restrict__ shift) {
    int c = threadIdx.x;
    const float invN = 1.0f / (float)N_NODES;
    float mu = colsum[c] * invN;
    float var = colsq[c] * invN - mu * mu;
    float rs = rsqrtf(var + BN_EPS) * g[c];
    scale[c] = rs;
    shift[c] = be[c] - mu * rs;
}

// ---- BN apply + ReLU + segmented pool (layer 2): one block per graph, NO atomics ----
__global__ __launch_bounds__(256) void bn_pool(const float* __restrict__ h,
                                               const float* __restrict__ scale,
                                               const float* __restrict__ shift,
                                               const int* __restrict__ gs,
                                               float* __restrict__ pooled) {
    int g = blockIdx.x;
    int t = threadIdx.x;
    int c4 = t & 31;   // float4 column group
    int rs = t >> 5;   // row stream 0..7
    int r0 = gs[g], r1 = gs[g + 1];
    f32x4 sc = ((const f32x4*)scale)[c4];
    f32x4 sh = ((const f32x4*)shift)[c4];
    f32x4 acc = f32x4{0.f, 0.f, 0.f, 0.f};
    for (int r = r0 + rs; r < r1; r += 8) {
        f32x4 v = ((const f32x4*)h)[(size_t)r * 32 + c4];
#pragma unroll
        for (int i = 0; i < 4; ++i) acc[i] += fmaxf(v[i] * sc[i] + sh[i], 0.f);
    }
    __shared__ f32x4 red[256];
    red[t] = acc;
    __syncthreads();
#pragma unroll
    for (int off = 128; off >= 32; off >>= 1) {
        if (t < off) red[t] += red[t + off];
        __syncthreads();
    }
    if (t < 32) ((f32x4*)pooled)[g * 32 + c4] = red[t];
}

// ---- final: out[g][c] = pooled[g] . Wo[:,c] + bo[c] ----
__global__ __launch_bounds__(256) void final_gemm(const float* __restrict__ pooled,
                                                  const float* __restrict__ Wo,
                                                  const float* __restrict__ bo,
                                                  float* __restrict__ out) {
    int t = blockIdx.x * 256 + threadIdx.x;
    if (t >= N_GRAPHS * N_CLASSES) return;
    int g = t / N_CLASSES, c = t - g * N_CLASSES;
    float s = bo[c];
    const float* p = pooled + (size_t)g * DIM;
#pragma unroll 4
    for (int k = 0; k < DIM; ++k) s += p[k] * Wo[k * N_CLASSES + c];
    out[t] = s;
}

extern "C" void kernel_launch(void* const* d_in, const int* in_sizes, int n_in,
                              void* d_out, int out_size, void* d_ws, size_t ws_size,
                              hipStream_t stream) {
    const float* x   = (const float*)d_in[0];
    const int* ei    = (const int*)d_in[1];   // harness: integer -> int32
    const int* batch = (const int*)d_in[2];
    const float* W1a = (const float*)d_in[3];
    const float* b1a = (const float*)d_in[4];
    const float* W1b = (const float*)d_in[5];
    const float* b1b = (const float*)d_in[6];
    const float* g1  = (const float*)d_in[7];
    const float* be1 = (const float*)d_in[8];
    const float* W2a = (const float*)d_in[9];
    const float* b2a = (const float*)d_in[10];
    const float* W2b = (const float*)d_in[11];
    const float* b2b = (const float*)d_in[12];
    const float* g2  = (const float*)d_in[13];
    const float* be2 = (const float*)d_in[14];
    const float* Wo  = (const float*)d_in[15];
    const float* bo  = (const float*)d_in[16];

    char* ws = (char*)d_ws;
    const size_t NB = (size_t)N_NODES * DIM * 4;  // 25,600,000 B
    float* agg = (float*)ws;
    float* hA  = (float*)(ws + NB);
    float* hB  = (float*)(ws + 2 * NB);
    unsigned short* wfrag = (unsigned short*)(ws + 3 * NB);  // 4*16384 bf16 = 128 KB
    char* smallb = ws + 3 * NB + 4 * 16384 * 2;
    float* colsum1 = (float*)smallb;
    float* colsq1  = colsum1 + 128;
    float* colsum2 = colsum1 + 256;
    float* colsq2  = colsum1 + 384;
    float* pooled  = colsum1 + 512;                // 128*128
    float* scale1  = pooled + N_GRAPHS * DIM;
    float* shift1  = scale1 + 128;
    float* scale2  = scale1 + 256;
    float* shift2  = scale1 + 384;
    int* gs        = (int*)(shift2 + 128);     // N_GRAPHS+1
    int* deg       = gs + N_GRAPHS + 1;
    int* row_start = deg + N_NODES;            // N_NODES+1
    int* cursor    = row_start + N_NODES + 1;
    int* csr_src   = cursor + N_NODES;         // N_EDGES

    // zero: colsums (4*128 floats); pooled is fully overwritten by bn_pool
    hipMemsetAsync(smallb, 0, 512 * 4, stream);
    hipMemsetAsync(deg, 0, N_NODES * 4, stream);

    prep_w<<<256, 256, 0, stream>>>(W1a, W1b, W2a, W2b, wfrag);
    graph_starts<<<1, 256, 0, stream>>>(batch, gs);

    // CSR build (per call; deterministic set, order-free sums)
    const int eblk = (N_EDGES + 255) / 256;
    hist_dst<<<eblk, 256, 0, stream>>>(ei, deg);
    scan_deg<<<1, 1024, 0, stream>>>(deg, row_start, cursor);
    fill_csr<<<eblk, 256, 0, stream>>>(ei, cursor, csr_src);

    const int ablk = (N_NODES + 3) / 4;
    const dim3 ggrid((N_NODES + 63) / 64, 2);

    // layer 1
    aggregate<false><<<ablk, 256, 0, stream>>>(x, agg, row_start, csr_src, nullptr, nullptr);
    gemm64<true, false><<<ggrid, 256, 0, stream>>>(
        agg, (const bf16x8*)(wfrag + 0 * 16384), b1a, hA, nullptr, nullptr, N_NODES);
    gemm64<false, true><<<ggrid, 256, 0, stream>>>(
        hA, (const bf16x8*)(wfrag + 1 * 16384), b1b, hB, colsum1, colsq1, N_NODES);
    bn_finalize<<<1, 128, 0, stream>>>(colsum1, colsq1, g1, be1, scale1, shift1);

    // layer 2 (BN1 fused into aggregate)
    aggregate<true><<<ablk, 256, 0, stream>>>(hB, agg, row_start, csr_src, scale1, shift1);
    gemm64<true, false><<<ggrid, 256, 0, stream>>>(
        agg, (const bf16x8*)(wfrag + 2 * 16384), b2a, hA, nullptr, nullptr, N_NODES);
    gemm64<false, true><<<ggrid, 256, 0, stream>>>(
        hA, (const bf16x8*)(wfrag + 3 * 16384), b2b, hB, colsum2, colsq2, N_NODES);
    bn_finalize<<<1, 128, 0, stream>>>(colsum2, colsq2, g2, be2, scale2, shift2);
    bn_pool<<<N_GRAPHS, 256, 0, stream>>>(hB, scale2, shift2, gs, pooled);

    final_gemm<<<(N_GRAPHS * N_CLASSES + 255) / 256, 256, 0, stream>>>(pooled, Wo, bo,
                                                                       (float*)d_out);
}

// Round 6
// 545.148 us; speedup vs baseline: 5.9141x; 1.2142x over previous
//
#include <hip/hip_runtime.h>

typedef __attribute__((ext_vector_type(8))) short bf16x8;
typedef __attribute__((ext_vector_type(4))) float f32x4;
typedef __attribute__((ext_vector_type(2))) float f32x2;

#define N_NODES 50000
#define N_EDGES 800000
#define DIM 128
#define N_GRAPHS 128
#define N_CLASSES 10
#define BN_EPS 1e-5f
#define SCAN_NB ((N_NODES + 255) / 256)   // 196

static __device__ __forceinline__ unsigned short f2bf(float f) {
    unsigned u = __float_as_uint(f);
    u += 0x7FFF + ((u >> 16) & 1);   // round-to-nearest-even
    return (unsigned short)(u >> 16);
}

// ---- CSR build: histogram of destinations ----
__global__ __launch_bounds__(256) void hist_dst(const int* __restrict__ ei, int* __restrict__ deg) {
    int e = blockIdx.x * 256 + threadIdx.x;
    if (e < N_EDGES) atomicAdd(&deg[ei[N_EDGES + e]], 1);
}

// ---- hierarchical scan, step 1: per-block sums ----
__global__ __launch_bounds__(256) void scan_reduce(const int* __restrict__ deg,
                                                   int* __restrict__ partials) {
    __shared__ int red[256];
    int idx = blockIdx.x * 256 + threadIdx.x;
    red[threadIdx.x] = (idx < N_NODES) ? deg[idx] : 0;
    __syncthreads();
#pragma unroll
    for (int off = 128; off >= 1; off >>= 1) {
        if (threadIdx.x < off) red[threadIdx.x] += red[threadIdx.x + off];
        __syncthreads();
    }
    if (threadIdx.x == 0) partials[blockIdx.x] = red[0];
}

// ---- hierarchical scan, step 2: exclusive scan of 196 partials (1 block) ----
__global__ __launch_bounds__(256) void scan_offsets(const int* __restrict__ partials,
                                                    int* __restrict__ offsets) {
    __shared__ int buf[256];
    int t = threadIdx.x;
    int v = (t < SCAN_NB) ? partials[t] : 0;
    buf[t] = v;
    __syncthreads();
#pragma unroll
    for (int off = 1; off < 256; off <<= 1) {
        int u = (t >= off) ? buf[t - off] : 0;
        __syncthreads();
        buf[t] += u;
        __syncthreads();
    }
    if (t < SCAN_NB) offsets[t] = buf[t] - v;   // exclusive
}

// ---- hierarchical scan, step 3: per-block scan + offset, write row_start & cursor ----
__global__ __launch_bounds__(256) void scan_apply(const int* __restrict__ deg,
                                                  const int* __restrict__ offsets,
                                                  int* __restrict__ row_start,
                                                  int* __restrict__ cursor) {
    __shared__ int buf[256];
    int t = threadIdx.x;
    int idx = blockIdx.x * 256 + t;
    int v = (idx < N_NODES) ? deg[idx] : 0;
    buf[t] = v;
    __syncthreads();
#pragma unroll
    for (int off = 1; off < 256; off <<= 1) {
        int u = (t >= off) ? buf[t - off] : 0;
        __syncthreads();
        buf[t] += u;
        __syncthreads();
    }
    int incl = buf[t] + offsets[blockIdx.x];
    int excl = incl - v;
    if (idx < N_NODES) {
        row_start[idx] = excl;
        cursor[idx] = excl;
        if (idx == N_NODES - 1) row_start[N_NODES] = incl;
    }
}

// ---- CSR build: scatter sources into per-dst segments ----
__global__ __launch_bounds__(256) void fill_csr(const int* __restrict__ ei,
                                                int* __restrict__ cursor,
                                                int* __restrict__ csr_src) {
    int e = blockIdx.x * 256 + threadIdx.x;
    if (e >= N_EDGES) return;
    int src = ei[e];
    int dst = ei[N_EDGES + e];
    int pos = atomicAdd(&cursor[dst], 1);
    csr_src[pos] = src;
}

// ---- graph segment starts via binary search (batch is sorted) ----
__global__ __launch_bounds__(256) void graph_starts(const int* __restrict__ batch,
                                                    int* __restrict__ gs) {
    int g = blockIdx.x * 256 + threadIdx.x;
    if (g > N_GRAPHS) return;
    int lo = 0, hi = N_NODES;
    while (lo < hi) {
        int mid = (lo + hi) >> 1;
        if (batch[mid] < g) lo = mid + 1; else hi = mid;
    }
    gs[g] = lo;
}

// ---- gather-sum aggregation; BN=true applies relu(f*scale+shift) per gathered row ----
// agg[v] = t(feat[v]) + sum_{e in CSR[v]} t(feat[src_e]),  t = BN? relu(bn(.)) : identity
template <bool BN>
__global__ __launch_bounds__(256) void aggregate(const float* __restrict__ feat,
                                                 float* __restrict__ agg,
                                                 const int* __restrict__ row_start,
                                                 const int* __restrict__ csr_src,
                                                 const float* __restrict__ scale,
                                                 const float* __restrict__ shift) {
    int wave = threadIdx.x >> 6, lane = threadIdx.x & 63;
    int v = blockIdx.x * 4 + wave;
    if (v >= N_NODES) return;
    const f32x2* F = (const f32x2*)feat;
    f32x2 sc, sh;
    if (BN) {
        sc = ((const f32x2*)scale)[lane];
        sh = ((const f32x2*)shift)[lane];
    }
    f32x2 t = F[(size_t)v * 64 + lane];
    f32x2 acc;
    if (BN) {
        acc[0] = fmaxf(t[0] * sc[0] + sh[0], 0.f);
        acc[1] = fmaxf(t[1] * sc[1] + sh[1], 0.f);
    } else {
        acc = t;
    }
    int e = row_start[v], end = row_start[v + 1];
    for (; e + 3 < end; e += 4) {
        int s0 = csr_src[e], s1 = csr_src[e + 1], s2 = csr_src[e + 2], s3 = csr_src[e + 3];
        f32x2 a = F[(size_t)s0 * 64 + lane];
        f32x2 b = F[(size_t)s1 * 64 + lane];
        f32x2 c = F[(size_t)s2 * 64 + lane];
        f32x2 d = F[(size_t)s3 * 64 + lane];
        if (BN) {
#pragma unroll
            for (int i = 0; i < 2; ++i) {
                a[i] = fmaxf(a[i] * sc[i] + sh[i], 0.f);
                b[i] = fmaxf(b[i] * sc[i] + sh[i], 0.f);
                c[i] = fmaxf(c[i] * sc[i] + sh[i], 0.f);
                d[i] = fmaxf(d[i] * sc[i] + sh[i], 0.f);
            }
        }
        acc += (a + b) + (c + d);
    }
    for (; e < end; ++e) {
        f32x2 a = F[(size_t)csr_src[e] * 64 + lane];
        if (BN) {
#pragma unroll
            for (int i = 0; i < 2; ++i) a[i] = fmaxf(a[i] * sc[i] + sh[i], 0.f);
        }
        acc += a;
    }
    ((f32x2*)agg)[(size_t)v * 64 + lane] = acc;
}

// ---- prep: permute W (f32 [128][128], row k, col j) into bf16 B-fragment layout ----
// frag layout: wf[m][ ((n*4+ks)*64 + lane)*8 + e ] = W[k][col],
//   col = n*16 + (lane&15),  k = ks*32 + (lane>>4)*8 + e
__global__ __launch_bounds__(256) void prep_w(const float* __restrict__ W0,
                                              const float* __restrict__ W1,
                                              const float* __restrict__ W2,
                                              const float* __restrict__ W3,
                                              unsigned short* __restrict__ wf) {
    int t = blockIdx.x * 256 + threadIdx.x;
    if (t >= 4 * 16384) return;
    int m = t >> 14, rem = t & 16383;
    int e = rem & 7, lane = (rem >> 3) & 63, fi = rem >> 9;
    int ks = fi & 3, n = fi >> 2;
    int col = n * 16 + (lane & 15);
    int k = ks * 32 + ((lane >> 4) << 3) + e;
    const float* W = (m == 0) ? W0 : (m == 1) ? W1 : (m == 2) ? W2 : W3;
    wf[t] = f2bf(W[k * DIM + col]);
}

// ---- GEMM: out[M, 64-col half] = A[M,128] @ W + bias; latency-optimized ----
// grid (rowTiles, 2); wave = 16 rows x 64 cols; ALL loads prefetched before MFMA
template <bool RELU, bool STATS>
__global__ __launch_bounds__(256, 2) void gemm64(const float* __restrict__ A,
                                                 const bf16x8* __restrict__ wfrag,
                                                 const float* __restrict__ bias,
                                                 float* __restrict__ out,
                                                 float* __restrict__ colsum,
                                                 float* __restrict__ colsq, int M) {
    int wave = threadIdx.x >> 6;
    int lane = threadIdx.x & 63;
    int r0 = blockIdx.x * 64 + wave * 16;
    int nh = blockIdx.y;               // column half: cols [nh*64, nh*64+64)
    int arow = r0 + (lane & 15);
    if (arow >= M) arow = M - 1;
    int kq = lane >> 4;  // 0..3

    // prefetch all 16 B fragments (independent 16B loads)
    bf16x8 bf[16];
#pragma unroll
    for (int i = 0; i < 16; ++i) bf[i] = wfrag[(nh * 16 + i) * 64 + lane];

    // prefetch all 8 A vectors
    const float* Ar = A + (size_t)arow * DIM + kq * 8;
    f32x4 a0[4], a1[4];
#pragma unroll
    for (int ks = 0; ks < 4; ++ks) {
        a0[ks] = *(const f32x4*)(Ar + ks * 32);
        a1[ks] = *(const f32x4*)(Ar + ks * 32 + 4);
    }

    // convert A to bf16 fragments: row = lane&15, k = kq*8 + e (+32 per ks)
    bf16x8 af[4];
#pragma unroll
    for (int ks = 0; ks < 4; ++ks) {
        bf16x8 a;
#pragma unroll
        for (int i = 0; i < 4; ++i) {
            a[i]     = (short)f2bf(a0[ks][i]);
            a[4 + i] = (short)f2bf(a1[ks][i]);
        }
        af[ks] = a;
    }

    f32x4 acc[4];
#pragma unroll
    for (int j = 0; j < 4; ++j) acc[j] = f32x4{0.f, 0.f, 0.f, 0.f};

#pragma unroll
    for (int j = 0; j < 4; ++j) {
#pragma unroll
        for (int ks = 0; ks < 4; ++ks) {
            acc[j] = __builtin_amdgcn_mfma_f32_16x16x32_bf16(af[ks], bf[j * 4 + ks],
                                                             acc[j], 0, 0, 0);
        }
    }

    // epilogue: D col = lane&15, row = kq*4 + reg (HW-verified layout)
    int colb = lane & 15;
    int rbase = r0 + kq * 4;
#pragma unroll
    for (int j = 0; j < 4; ++j) {
        int col = nh * 64 + j * 16 + colb;
        float b = bias[col];
        float s = 0.f, q = 0.f;
#pragma unroll
        for (int r = 0; r < 4; ++r) {
            int row = rbase + r;
            float v = acc[j][r] + b;
            if (RELU) v = fmaxf(v, 0.f);
            if (row < M) {
                out[(size_t)row * DIM + col] = v;
                if (STATS) { s += v; q += v * v; }
            }
        }
        if (STATS) {
            s += __shfl_xor(s, 16, 64);
            s += __shfl_xor(s, 32, 64);
            q += __shfl_xor(q, 16, 64);
            q += __shfl_xor(q, 32, 64);
            if (kq == 0) {
                unsafeAtomicAdd(&colsum[col], s);
                unsafeAtomicAdd(&colsq[col], q);
            }
        }
    }
}

// ---- BN finalize ----
__global__ __launch_bounds__(128) void bn_finalize(const float* __restrict__ colsum,
                                                   const float* __restrict__ colsq,
                                                   const float* __restrict__ g,
                                                   const float* __restrict__ be,
                                                   float* __restrict__ scale,
                                                   float* __restrict__ shift) {
    int c = threadIdx.x;
    const float invN = 1.0f / (float)N_NODES;
    float mu = colsum[c] * invN;
    float var = colsq[c] * invN - mu * mu;
    float rs = rsqrtf(var + BN_EPS) * g[c];
    scale[c] = rs;
    shift[c] = be[c] - mu * rs;
}

// ---- BN apply + ReLU + segmented pool (layer 2): one block per graph, NO atomics ----
__global__ __launch_bounds__(256) void bn_pool(const float* __restrict__ h,
                                               const float* __restrict__ scale,
                                               const float* __restrict__ shift,
                                               const int* __restrict__ gs,
                                               float* __restrict__ pooled) {
    int g = blockIdx.x;
    int t = threadIdx.x;
    int c4 = t & 31;   // float4 column group
    int rs = t >> 5;   // row stream 0..7
    int r0 = gs[g], r1 = gs[g + 1];
    f32x4 sc = ((const f32x4*)scale)[c4];
    f32x4 sh = ((const f32x4*)shift)[c4];
    f32x4 acc = f32x4{0.f, 0.f, 0.f, 0.f};
    for (int r = r0 + rs; r < r1; r += 8) {
        f32x4 v = ((const f32x4*)h)[(size_t)r * 32 + c4];
#pragma unroll
        for (int i = 0; i < 4; ++i) acc[i] += fmaxf(v[i] * sc[i] + sh[i], 0.f);
    }
    __shared__ f32x4 red[256];
    red[t] = acc;
    __syncthreads();
#pragma unroll
    for (int off = 128; off >= 32; off >>= 1) {
        if (t < off) red[t] += red[t + off];
        __syncthreads();
    }
    if (t < 32) ((f32x4*)pooled)[g * 32 + c4] = red[t];
}

// ---- final: out[g][c] = pooled[g] . Wo[:,c] + bo[c] ----
__global__ __launch_bounds__(256) void final_gemm(const float* __restrict__ pooled,
                                                  const float* __restrict__ Wo,
                                                  const float* __restrict__ bo,
                                                  float* __restrict__ out) {
    int t = blockIdx.x * 256 + threadIdx.x;
    if (t >= N_GRAPHS * N_CLASSES) return;
    int g = t / N_CLASSES, c = t - g * N_CLASSES;
    float s = bo[c];
    const float* p = pooled + (size_t)g * DIM;
#pragma unroll 4
    for (int k = 0; k < DIM; ++k) s += p[k] * Wo[k * N_CLASSES + c];
    out[t] = s;
}

extern "C" void kernel_launch(void* const* d_in, const int* in_sizes, int n_in,
                              void* d_out, int out_size, void* d_ws, size_t ws_size,
                              hipStream_t stream) {
    const float* x   = (const float*)d_in[0];
    const int* ei    = (const int*)d_in[1];   // harness: integer -> int32
    const int* batch = (const int*)d_in[2];
    const float* W1a = (const float*)d_in[3];
    const float* b1a = (const float*)d_in[4];
    const float* W1b = (const float*)d_in[5];
    const float* b1b = (const float*)d_in[6];
    const float* g1  = (const float*)d_in[7];
    const float* be1 = (const float*)d_in[8];
    const float* W2a = (const float*)d_in[9];
    const float* b2a = (const float*)d_in[10];
    const float* W2b = (const float*)d_in[11];
    const float* b2b = (const float*)d_in[12];
    const float* g2  = (const float*)d_in[13];
    const float* be2 = (const float*)d_in[14];
    const float* Wo  = (const float*)d_in[15];
    const float* bo  = (const float*)d_in[16];

    char* ws = (char*)d_ws;
    const size_t NB = (size_t)N_NODES * DIM * 4;  // 25,600,000 B
    float* agg = (float*)ws;
    float* hA  = (float*)(ws + NB);
    float* hB  = (float*)(ws + 2 * NB);
    unsigned short* wfrag = (unsigned short*)(ws + 3 * NB);  // 4*16384 bf16 = 128 KB
    char* smallb = ws + 3 * NB + 4 * 16384 * 2;
    float* colsum1 = (float*)smallb;
    float* colsq1  = colsum1 + 128;
    float* colsum2 = colsum1 + 256;
    float* colsq2  = colsum1 + 384;
    float* pooled  = colsum1 + 512;                // 128*128
    float* scale1  = pooled + N_GRAPHS * DIM;
    float* shift1  = scale1 + 128;
    float* scale2  = scale1 + 256;
    float* shift2  = scale1 + 384;
    int* gs        = (int*)(shift2 + 128);     // N_GRAPHS+1
    int* deg       = gs + N_GRAPHS + 1;
    int* row_start = deg + N_NODES;            // N_NODES+1
    int* cursor    = row_start + N_NODES + 1;
    int* partials  = cursor + N_NODES;         // SCAN_NB
    int* offsets   = partials + SCAN_NB;       // SCAN_NB
    int* csr_src   = offsets + SCAN_NB;        // N_EDGES

    // zero: colsums (4*128 floats); pooled is fully overwritten by bn_pool
    hipMemsetAsync(smallb, 0, 512 * 4, stream);
    hipMemsetAsync(deg, 0, N_NODES * 4, stream);

    prep_w<<<256, 256, 0, stream>>>(W1a, W1b, W2a, W2b, wfrag);
    graph_starts<<<1, 256, 0, stream>>>(batch, gs);

    // CSR build (per call; deterministic set, order-free sums)
    const int eblk = (N_EDGES + 255) / 256;
    hist_dst<<<eblk, 256, 0, stream>>>(ei, deg);
    scan_reduce<<<SCAN_NB, 256, 0, stream>>>(deg, partials);
    scan_offsets<<<1, 256, 0, stream>>>(partials, offsets);
    scan_apply<<<SCAN_NB, 256, 0, stream>>>(deg, offsets, row_start, cursor);
    fill_csr<<<eblk, 256, 0, stream>>>(ei, cursor, csr_src);

    const int ablk = (N_NODES + 3) / 4;
    const dim3 ggrid((N_NODES + 63) / 64, 2);

    // layer 1
    aggregate<false><<<ablk, 256, 0, stream>>>(x, agg, row_start, csr_src, nullptr, nullptr);
    gemm64<true, false><<<ggrid, 256, 0, stream>>>(
        agg, (const bf16x8*)(wfrag + 0 * 16384), b1a, hA, nullptr, nullptr, N_NODES);
    gemm64<false, true><<<ggrid, 256, 0, stream>>>(
        hA, (const bf16x8*)(wfrag + 1 * 16384), b1b, hB, colsum1, colsq1, N_NODES);
    bn_finalize<<<1, 128, 0, stream>>>(colsum1, colsq1, g1, be1, scale1, shift1);

    // layer 2 (BN1 fused into aggregate)
    aggregate<true><<<ablk, 256, 0, stream>>>(hB, agg, row_start, csr_src, scale1, shift1);
    gemm64<true, false><<<ggrid, 256, 0, stream>>>(
        agg, (const bf16x8*)(wfrag + 2 * 16384), b2a, hA, nullptr, nullptr, N_NODES);
    gemm64<false, true><<<ggrid, 256, 0, stream>>>(
        hA, (const bf16x8*)(wfrag + 3 * 16384), b2b, hB, colsum2, colsq2, N_NODES);
    bn_finalize<<<1, 128, 0, stream>>>(colsum2, colsq2, g2, be2, scale2, shift2);
    bn_pool<<<N_GRAPHS, 256, 0, stream>>>(hB, scale2, shift2, gs, pooled);

    final_gemm<<<(N_GRAPHS * N_CLASSES + 255) / 256, 256, 0, stream>>>(pooled, Wo, bo,
                                                                       (float*)d_out);
}

// Round 7
// 449.749 us; speedup vs baseline: 7.1685x; 1.2121x over previous
//
#include <hip/hip_runtime.h>

typedef __attribute__((ext_vector_type(8))) short bf16x8;
typedef __attribute__((ext_vector_type(4))) float f32x4;
typedef __attribute__((ext_vector_type(2))) float f32x2;
typedef __attribute__((ext_vector_type(2))) unsigned u32x2;

#define N_NODES 50000
#define N_EDGES 800000
#define DIM 128
#define N_GRAPHS 128
#define N_CLASSES 10
#define BN_EPS 1e-5f
#define SCAN_NB ((N_NODES + 255) / 256)   // 196

static __device__ __forceinline__ unsigned short f2bf(float f) {
    unsigned u = __float_as_uint(f);
    u += 0x7FFF + ((u >> 16) & 1);   // round-to-nearest-even
    return (unsigned short)(u >> 16);
}
static __device__ __forceinline__ float bf_lo(unsigned u) { return __uint_as_float(u << 16); }
static __device__ __forceinline__ float bf_hi(unsigned u) { return __uint_as_float(u & 0xffff0000u); }
static __device__ __forceinline__ unsigned packbf(float a, float b) {
    return (unsigned)f2bf(a) | ((unsigned)f2bf(b) << 16);
}

// ---- x (f32) -> xb (bf16 packed) ----
__global__ __launch_bounds__(256) void cvt_x(const f32x2* __restrict__ x,
                                             unsigned* __restrict__ xb, int n) {
    int t = blockIdx.x * 256 + threadIdx.x;
    if (t < n) { f32x2 v = x[t]; xb[t] = packbf(v[0], v[1]); }
}

// ---- CSR build: histogram of destinations ----
__global__ __launch_bounds__(256) void hist_dst(const int* __restrict__ ei, int* __restrict__ deg) {
    int e = blockIdx.x * 256 + threadIdx.x;
    if (e < N_EDGES) atomicAdd(&deg[ei[N_EDGES + e]], 1);
}

// ---- hierarchical scan ----
__global__ __launch_bounds__(256) void scan_reduce(const int* __restrict__ deg,
                                                   int* __restrict__ partials) {
    __shared__ int red[256];
    int idx = blockIdx.x * 256 + threadIdx.x;
    red[threadIdx.x] = (idx < N_NODES) ? deg[idx] : 0;
    __syncthreads();
#pragma unroll
    for (int off = 128; off >= 1; off >>= 1) {
        if (threadIdx.x < off) red[threadIdx.x] += red[threadIdx.x + off];
        __syncthreads();
    }
    if (threadIdx.x == 0) partials[blockIdx.x] = red[0];
}

__global__ __launch_bounds__(256) void scan_offsets(const int* __restrict__ partials,
                                                    int* __restrict__ offsets) {
    __shared__ int buf[256];
    int t = threadIdx.x;
    int v = (t < SCAN_NB) ? partials[t] : 0;
    buf[t] = v;
    __syncthreads();
#pragma unroll
    for (int off = 1; off < 256; off <<= 1) {
        int u = (t >= off) ? buf[t - off] : 0;
        __syncthreads();
        buf[t] += u;
        __syncthreads();
    }
    if (t < SCAN_NB) offsets[t] = buf[t] - v;
}

__global__ __launch_bounds__(256) void scan_apply(const int* __restrict__ deg,
                                                  const int* __restrict__ offsets,
                                                  int* __restrict__ row_start,
                                                  int* __restrict__ cursor) {
    __shared__ int buf[256];
    int t = threadIdx.x;
    int idx = blockIdx.x * 256 + t;
    int v = (idx < N_NODES) ? deg[idx] : 0;
    buf[t] = v;
    __syncthreads();
#pragma unroll
    for (int off = 1; off < 256; off <<= 1) {
        int u = (t >= off) ? buf[t - off] : 0;
        __syncthreads();
        buf[t] += u;
        __syncthreads();
    }
    int incl = buf[t] + offsets[blockIdx.x];
    int excl = incl - v;
    if (idx < N_NODES) {
        row_start[idx] = excl;
        cursor[idx] = excl;
        if (idx == N_NODES - 1) row_start[N_NODES] = incl;
    }
}

__global__ __launch_bounds__(256) void fill_csr(const int* __restrict__ ei,
                                                int* __restrict__ cursor,
                                                int* __restrict__ csr_src) {
    int e = blockIdx.x * 256 + threadIdx.x;
    if (e >= N_EDGES) return;
    int src = ei[e];
    int dst = ei[N_EDGES + e];
    int pos = atomicAdd(&cursor[dst], 1);
    csr_src[pos] = src;
}

// ---- graph segment starts via binary search (batch is sorted) ----
__global__ __launch_bounds__(256) void graph_starts(const int* __restrict__ batch,
                                                    int* __restrict__ gs) {
    int g = blockIdx.x * 256 + threadIdx.x;
    if (g > N_GRAPHS) return;
    int lo = 0, hi = N_NODES;
    while (lo < hi) {
        int mid = (lo + hi) >> 1;
        if (batch[mid] < g) lo = mid + 1; else hi = mid;
    }
    gs[g] = lo;
}

// ---- gather-sum aggregation on bf16 features; BN=true applies relu(f*sc+sh) ----
// one wave per node; lane holds 2 cols packed in u32
template <bool BN>
__global__ __launch_bounds__(256) void aggregate_bf(const unsigned* __restrict__ F,
                                                    unsigned* __restrict__ out,
                                                    const int* __restrict__ row_start,
                                                    const int* __restrict__ csr_src,
                                                    const float* __restrict__ scale,
                                                    const float* __restrict__ shift) {
    int wave = threadIdx.x >> 6, lane = threadIdx.x & 63;
    int v = blockIdx.x * 4 + wave;
    if (v >= N_NODES) return;
    float sc0 = 0.f, sc1 = 0.f, sh0 = 0.f, sh1 = 0.f;
    if (BN) {
        f32x2 s2 = ((const f32x2*)scale)[lane];
        f32x2 h2 = ((const f32x2*)shift)[lane];
        sc0 = s2[0]; sc1 = s2[1]; sh0 = h2[0]; sh1 = h2[1];
    }
    unsigned u = F[(size_t)v * 64 + lane];
    float a0 = bf_lo(u), a1 = bf_hi(u);
    if (BN) { a0 = fmaxf(a0 * sc0 + sh0, 0.f); a1 = fmaxf(a1 * sc1 + sh1, 0.f); }
    int e = row_start[v], end = row_start[v + 1];
    for (; e + 3 < end; e += 4) {
        unsigned ua = F[(size_t)csr_src[e] * 64 + lane];
        unsigned ub = F[(size_t)csr_src[e + 1] * 64 + lane];
        unsigned uc = F[(size_t)csr_src[e + 2] * 64 + lane];
        unsigned ud = F[(size_t)csr_src[e + 3] * 64 + lane];
        float p0 = bf_lo(ua), p1 = bf_hi(ua), q0 = bf_lo(ub), q1 = bf_hi(ub);
        float r0 = bf_lo(uc), r1 = bf_hi(uc), s0 = bf_lo(ud), s1 = bf_hi(ud);
        if (BN) {
            p0 = fmaxf(p0 * sc0 + sh0, 0.f); p1 = fmaxf(p1 * sc1 + sh1, 0.f);
            q0 = fmaxf(q0 * sc0 + sh0, 0.f); q1 = fmaxf(q1 * sc1 + sh1, 0.f);
            r0 = fmaxf(r0 * sc0 + sh0, 0.f); r1 = fmaxf(r1 * sc1 + sh1, 0.f);
            s0 = fmaxf(s0 * sc0 + sh0, 0.f); s1 = fmaxf(s1 * sc1 + sh1, 0.f);
        }
        a0 += (p0 + q0) + (r0 + s0);
        a1 += (p1 + q1) + (r1 + s1);
    }
    for (; e < end; ++e) {
        unsigned ua = F[(size_t)csr_src[e] * 64 + lane];
        float p0 = bf_lo(ua), p1 = bf_hi(ua);
        if (BN) { p0 = fmaxf(p0 * sc0 + sh0, 0.f); p1 = fmaxf(p1 * sc1 + sh1, 0.f); }
        a0 += p0; a1 += p1;
    }
    out[(size_t)v * 64 + lane] = packbf(a0, a1);
}

// ---- prep: permute W (f32 [128][128]) into bf16 B-fragment layout ----
// wf[m][ ((n*4+ks)*64 + lane)*8 + e ] = W[k][col], col=n*16+(lane&15), k=ks*32+(lane>>4)*8+e
__global__ __launch_bounds__(256) void prep_w(const float* __restrict__ W0,
                                              const float* __restrict__ W1,
                                              const float* __restrict__ W2,
                                              const float* __restrict__ W3,
                                              unsigned short* __restrict__ wf) {
    int t = blockIdx.x * 256 + threadIdx.x;
    if (t >= 4 * 16384) return;
    int m = t >> 14, rem = t & 16383;
    int e = rem & 7, lane = (rem >> 3) & 63, fi = rem >> 9;
    int ks = fi & 3, n = fi >> 2;
    int col = n * 16 + (lane & 15);
    int k = ks * 32 + ((lane >> 4) << 3) + e;
    const float* W = (m == 0) ? W0 : (m == 1) ? W1 : (m == 2) ? W2 : W3;
    wf[t] = f2bf(W[k * DIM + col]);
}

// ---- fused GIN layer: h = relu(A@Wa + ba) @ Wb + bb, col stats of h ----
// 256 thr = 4 waves; block = 64 rows; wave = 16 rows x 128 cols, both GEMMs
// LDS: wfA(32K) + wfB(32K) + mid(16K, XOR-swizzled) = 80 KB -> 2 blocks/CU
__global__ __launch_bounds__(256, 2) void fused_layer(
        const unsigned short* __restrict__ A,   // [M][128] bf16
        const bf16x8* __restrict__ wfA_g,       // 2048 frags
        const bf16x8* __restrict__ wfB_g,
        const float* __restrict__ bias_a,
        const float* __restrict__ bias_b,
        unsigned short* __restrict__ out,       // [M][128] bf16
        float* __restrict__ colsum, float* __restrict__ colsq, int M) {
    __shared__ bf16x8 wfA[2048];
    __shared__ bf16x8 wfB[2048];
    __shared__ unsigned short mid[8192];        // 64 x 128

    int tid = threadIdx.x;
#pragma unroll
    for (int i = 0; i < 8; ++i) wfA[i * 256 + tid] = wfA_g[i * 256 + tid];
#pragma unroll
    for (int i = 0; i < 8; ++i) wfB[i * 256 + tid] = wfB_g[i * 256 + tid];

    int w = tid >> 6, lane = tid & 63;
    int cl = lane & 15, kq = lane >> 4;
    int rblk = blockIdx.x * 64;

    // A1 fragments: coalesced 16B/lane from row-major bf16
    int arow = rblk + w * 16 + cl;
    if (arow >= M) arow = M - 1;
    bf16x8 af[4];
    const unsigned short* Ap = A + (size_t)arow * DIM + kq * 8;
#pragma unroll
    for (int ks = 0; ks < 4; ++ks) af[ks] = *(const bf16x8*)(Ap + ks * 32);

    __syncthreads();   // wf staged

    // GEMM1
    f32x4 acc[8];
#pragma unroll
    for (int n = 0; n < 8; ++n) acc[n] = f32x4{0.f, 0.f, 0.f, 0.f};
#pragma unroll
    for (int n = 0; n < 8; ++n)
#pragma unroll
        for (int ks = 0; ks < 4; ++ks)
            acc[n] = __builtin_amdgcn_mfma_f32_16x16x32_bf16(af[ks], wfA[(n * 4 + ks) * 64 + lane],
                                                             acc[n], 0, 0, 0);

    // epilogue 1: bias + relu -> mid (bf16, swizzled idx ^ ((row&7)<<3))
#pragma unroll
    for (int n = 0; n < 8; ++n) {
        int col = n * 16 + cl;
        float b = bias_a[col];
#pragma unroll
        for (int r = 0; r < 4; ++r) {
            int rl = w * 16 + kq * 4 + r;
            float v = fmaxf(acc[n][r] + b, 0.f);
            mid[(rl * DIM + col) ^ ((rl & 7) << 3)] = f2bf(v);
        }
    }
    __syncthreads();

    // A2 fragments from mid (ds_read_b128)
    bf16x8 af2[4];
    {
        int rl = w * 16 + cl;
        int sw = (cl & 7) << 3;
#pragma unroll
        for (int ks = 0; ks < 4; ++ks)
            af2[ks] = *(const bf16x8*)(mid + ((rl * DIM + kq * 8 + ks * 32) ^ sw));
    }

    // GEMM2
    f32x4 acc2[8];
#pragma unroll
    for (int n = 0; n < 8; ++n) acc2[n] = f32x4{0.f, 0.f, 0.f, 0.f};
#pragma unroll
    for (int n = 0; n < 8; ++n)
#pragma unroll
        for (int ks = 0; ks < 4; ++ks)
            acc2[n] = __builtin_amdgcn_mfma_f32_16x16x32_bf16(af2[ks], wfB[(n * 4 + ks) * 64 + lane],
                                                              acc2[n], 0, 0, 0);

    // epilogue 2: bias + stats; park bf16 in mid for coalesced store
#pragma unroll
    for (int n = 0; n < 8; ++n) {
        int col = n * 16 + cl;
        float b = bias_b[col];
        float s = 0.f, q = 0.f;
#pragma unroll
        for (int r = 0; r < 4; ++r) {
            int rl = w * 16 + kq * 4 + r;
            float v = acc2[n][r] + b;
            if (rblk + rl < M) { s += v; q += v * v; }
            mid[(rl * DIM + col) ^ ((rl & 7) << 3)] = f2bf(v);
        }
        s += __shfl_xor(s, 16, 64);
        s += __shfl_xor(s, 32, 64);
        q += __shfl_xor(q, 16, 64);
        q += __shfl_xor(q, 32, 64);
        if (kq == 0) {
            unsafeAtomicAdd(&colsum[col], s);
            unsafeAtomicAdd(&colsq[col], q);
        }
    }

    // bounce-store: 4 x fully-coalesced 1KB store instructions per wave
    {
        int r4 = lane >> 4, c = lane & 15;
#pragma unroll
        for (int rb = 0; rb < 4; ++rb) {
            int rl = w * 16 + rb * 4 + r4;
            int grow = rblk + rl;
            bf16x8 v = *(const bf16x8*)(mid + ((rl * DIM + c * 8) ^ ((rl & 7) << 3)));
            if (grow < M) *(bf16x8*)(out + (size_t)grow * DIM + c * 8) = v;
        }
    }
}

// ---- BN finalize ----
__global__ __launch_bounds__(128) void bn_finalize(const float* __restrict__ colsum,
                                                   const float* __restrict__ colsq,
                                                   const float* __restrict__ g,
                                                   const float* __restrict__ be,
                                                   float* __restrict__ scale,
                                                   float* __restrict__ shift) {
    int c = threadIdx.x;
    const float invN = 1.0f / (float)N_NODES;
    float mu = colsum[c] * invN;
    float var = colsq[c] * invN - mu * mu;
    float rs = rsqrtf(var + BN_EPS) * g[c];
    scale[c] = rs;
    shift[c] = be[c] - mu * rs;
}

// ---- BN apply + ReLU + segmented pool (bf16 input): one block per graph ----
__global__ __launch_bounds__(256) void bn_pool(const unsigned short* __restrict__ h,
                                               const float* __restrict__ scale,
                                               const float* __restrict__ shift,
                                               const int* __restrict__ gs,
                                               float* __restrict__ pooled) {
    int g = blockIdx.x;
    int t = threadIdx.x;
    int c4 = t & 31;   // 4-col group
    int rs = t >> 5;   // row stream 0..7
    int r0 = gs[g], r1 = gs[g + 1];
    f32x4 sc = ((const f32x4*)scale)[c4];
    f32x4 sh = ((const f32x4*)shift)[c4];
    f32x4 acc = f32x4{0.f, 0.f, 0.f, 0.f};
    for (int r = r0 + rs; r < r1; r += 8) {
        u32x2 u = *(const u32x2*)(h + (size_t)r * DIM + c4 * 4);
        float f0 = bf_lo(u[0]), f1 = bf_hi(u[0]), f2 = bf_lo(u[1]), f3 = bf_hi(u[1]);
        acc[0] += fmaxf(f0 * sc[0] + sh[0], 0.f);
        acc[1] += fmaxf(f1 * sc[1] + sh[1], 0.f);
        acc[2] += fmaxf(f2 * sc[2] + sh[2], 0.f);
        acc[3] += fmaxf(f3 * sc[3] + sh[3], 0.f);
    }
    __shared__ f32x4 red[256];
    red[t] = acc;
    __syncthreads();
#pragma unroll
    for (int off = 128; off >= 32; off >>= 1) {
        if (t < off) red[t] += red[t + off];
        __syncthreads();
    }
    if (t < 32) ((f32x4*)pooled)[g * 32 + c4] = red[t];
}

// ---- final: out[g][c] = pooled[g] . Wo[:,c] + bo[c] ----
__global__ __launch_bounds__(256) void final_gemm(const float* __restrict__ pooled,
                                                  const float* __restrict__ Wo,
                                                  const float* __restrict__ bo,
                                                  float* __restrict__ out) {
    int t = blockIdx.x * 256 + threadIdx.x;
    if (t >= N_GRAPHS * N_CLASSES) return;
    int g = t / N_CLASSES, c = t - g * N_CLASSES;
    float s = bo[c];
    const float* p = pooled + (size_t)g * DIM;
#pragma unroll 4
    for (int k = 0; k < DIM; ++k) s += p[k] * Wo[k * N_CLASSES + c];
    out[t] = s;
}

extern "C" void kernel_launch(void* const* d_in, const int* in_sizes, int n_in,
                              void* d_out, int out_size, void* d_ws, size_t ws_size,
                              hipStream_t stream) {
    const float* x   = (const float*)d_in[0];
    const int* ei    = (const int*)d_in[1];   // harness: integer -> int32
    const int* batch = (const int*)d_in[2];
    const float* W1a = (const float*)d_in[3];
    const float* b1a = (const float*)d_in[4];
    const float* W1b = (const float*)d_in[5];
    const float* b1b = (const float*)d_in[6];
    const float* g1  = (const float*)d_in[7];
    const float* be1 = (const float*)d_in[8];
    const float* W2a = (const float*)d_in[9];
    const float* b2a = (const float*)d_in[10];
    const float* W2b = (const float*)d_in[11];
    const float* b2b = (const float*)d_in[12];
    const float* g2  = (const float*)d_in[13];
    const float* be2 = (const float*)d_in[14];
    const float* Wo  = (const float*)d_in[15];
    const float* bo  = (const float*)d_in[16];

    char* ws = (char*)d_ws;
    const size_t NBH = (size_t)N_NODES * DIM * 2;   // 12.8 MB (bf16 node features)
    unsigned short* xb   = (unsigned short*)ws;
    unsigned short* aggb = (unsigned short*)(ws + NBH);
    unsigned short* hb   = (unsigned short*)(ws + 2 * NBH);
    unsigned short* wfrag = (unsigned short*)(ws + 3 * NBH);   // 4*16384 bf16 = 128 KB
    char* smallb = ws + 3 * NBH + 4 * 16384 * 2;
    float* colsum1 = (float*)smallb;
    float* colsq1  = colsum1 + 128;
    float* colsum2 = colsum1 + 256;
    float* colsq2  = colsum1 + 384;
    float* pooled  = colsum1 + 512;                // 128*128
    float* scale1  = pooled + N_GRAPHS * DIM;
    float* shift1  = scale1 + 128;
    float* scale2  = scale1 + 256;
    float* shift2  = scale1 + 384;
    int* gs        = (int*)(shift2 + 128);     // N_GRAPHS+1
    int* deg       = gs + N_GRAPHS + 1;
    int* row_start = deg + N_NODES;            // N_NODES+1
    int* cursor    = row_start + N_NODES + 1;
    int* partials  = cursor + N_NODES;         // SCAN_NB
    int* offsets   = partials + SCAN_NB;       // SCAN_NB
    int* csr_src   = offsets + SCAN_NB;        // N_EDGES

    hipMemsetAsync(smallb, 0, 512 * 4, stream);
    hipMemsetAsync(deg, 0, N_NODES * 4, stream);

    const int nv2 = N_NODES * 64;  // f32x2 count
    cvt_x<<<(nv2 + 255) / 256, 256, 0, stream>>>((const f32x2*)x, (unsigned*)xb, nv2);
    prep_w<<<256, 256, 0, stream>>>(W1a, W1b, W2a, W2b, wfrag);
    graph_starts<<<1, 256, 0, stream>>>(batch, gs);

    const int eblk = (N_EDGES + 255) / 256;
    hist_dst<<<eblk, 256, 0, stream>>>(ei, deg);
    scan_reduce<<<SCAN_NB, 256, 0, stream>>>(deg, partials);
    scan_offsets<<<1, 256, 0, stream>>>(partials, offsets);
    scan_apply<<<SCAN_NB, 256, 0, stream>>>(deg, offsets, row_start, cursor);
    fill_csr<<<eblk, 256, 0, stream>>>(ei, cursor, csr_src);

    const int ablk = (N_NODES + 3) / 4;
    const int fblk = (N_NODES + 63) / 64;

    // layer 1
    aggregate_bf<false><<<ablk, 256, 0, stream>>>((const unsigned*)xb, (unsigned*)aggb,
                                                  row_start, csr_src, nullptr, nullptr);
    fused_layer<<<fblk, 256, 0, stream>>>(
        aggb, (const bf16x8*)(wfrag + 0 * 16384), (const bf16x8*)(wfrag + 1 * 16384),
        b1a, b1b, hb, colsum1, colsq1, N_NODES);
    bn_finalize<<<1, 128, 0, stream>>>(colsum1, colsq1, g1, be1, scale1, shift1);

    // layer 2 (BN1+ReLU fused into aggregate)
    aggregate_bf<true><<<ablk, 256, 0, stream>>>((const unsigned*)hb, (unsigned*)aggb,
                                                 row_start, csr_src, scale1, shift1);
    fused_layer<<<fblk, 256, 0, stream>>>(
        aggb, (const bf16x8*)(wfrag + 2 * 16384), (const bf16x8*)(wfrag + 3 * 16384),
        b2a, b2b, hb, colsum2, colsq2, N_NODES);
    bn_finalize<<<1, 128, 0, stream>>>(colsum2, colsq2, g2, be2, scale2, shift2);
    bn_pool<<<N_GRAPHS, 256, 0, stream>>>(hb, scale2, shift2, gs, pooled);

    final_gemm<<<(N_GRAPHS * N_CLASSES + 255) / 256, 256, 0, stream>>>(pooled, Wo, bo,
                                                                       (float*)d_out);
}